// Round 4
// baseline (1235.557 us; speedup 1.0000x reference)
//
#include <hip/hip_runtime.h>
#include <cstdint>
#include <cstddef>

#define BNR 16384   // b*n rows
#define C   512     // feature dim
#define M   8192    // codebook size
#define K3  1536    // 3x expanded K (hi,hi,lo) x (hi,lo,hi)
#define NSPLIT 8
#define NTILES 8    // 128-col tiles per split
#define NSETS  16   // NSPLIT * 2 column-halves

typedef float f32x4 __attribute__((ext_vector_type(4)));
typedef short s16x8 __attribute__((ext_vector_type(8)));
typedef unsigned short u16;

static __device__ __forceinline__ u16 f2bf(float f) {
    unsigned u = __float_as_uint(f);
    unsigned r = (u + 0x7FFFu + ((u >> 16) & 1u)) >> 16;
    return (u16)r;
}
static __device__ __forceinline__ float bf2f(u16 b) {
    return __uint_as_float(((unsigned)b) << 16);
}
static __device__ __forceinline__ void gl_lds16(const void* g, void* l) {
    __builtin_amdgcn_global_load_lds(
        (const __attribute__((address_space(1))) void*)g,
        (__attribute__((address_space(3))) void*)l, 16, 0, 0);
}

// ---------------- ||k||^2 per codebook row (exact fp32) ----------------
__global__ void knorm_k(const float* __restrict__ emb, float* __restrict__ knorm) {
    int gw   = (blockIdx.x * blockDim.x + threadIdx.x) >> 6;
    int lane = threadIdx.x & 63;
    int nw   = (gridDim.x * blockDim.x) >> 6;
    for (int row = gw; row < M; row += nw) {
        const float4* p = (const float4*)(emb + (size_t)row * C);
        float s = 0.f;
#pragma unroll
        for (int j = 0; j < 2; ++j) {
            float4 v = p[lane + 64 * j];
            s += v.x * v.x + v.y * v.y + v.z * v.z + v.w * v.w;
        }
#pragma unroll
        for (int o = 32; o > 0; o >>= 1) s += __shfl_down(s, o, 64);
        if (lane == 0) knorm[row] = s;
    }
}

// ---------------- fp32 -> split-bf16 triples ----------------
// x side: {hi, hi, lo}
__global__ void cvt_x_k(const float* __restrict__ in, u16* __restrict__ outp) {
    int t = blockIdx.x * 256 + threadIdx.x;     // one float4 per thread
    int row = t >> 7;                           // 128 float4 per row
    int c4  = t & 127;
    float4 v = *(const float4*)(in + ((size_t)row << 9) + c4 * 4);
    float e[4] = { v.x, v.y, v.z, v.w };
    u16 o[12];
#pragma unroll
    for (int j = 0; j < 4; ++j) {
        u16 h = f2bf(e[j]);
        u16 l = f2bf(e[j] - bf2f(h));
        o[3 * j + 0] = h; o[3 * j + 1] = h; o[3 * j + 2] = l;
    }
    u16* dst = outp + (size_t)row * K3 + c4 * 12;
#pragma unroll
    for (int j = 0; j < 3; ++j) *(ushort4*)(dst + 4 * j) = *(ushort4*)(o + 4 * j);
}
// emb side: {hi, lo, hi}
__global__ void cvt_e_k(const float* __restrict__ in, u16* __restrict__ outp) {
    int t = blockIdx.x * 256 + threadIdx.x;
    int row = t >> 7;
    int c4  = t & 127;
    float4 v = *(const float4*)(in + ((size_t)row << 9) + c4 * 4);
    float e[4] = { v.x, v.y, v.z, v.w };
    u16 o[12];
#pragma unroll
    for (int j = 0; j < 4; ++j) {
        u16 h = f2bf(e[j]);
        u16 l = f2bf(e[j] - bf2f(h));
        o[3 * j + 0] = h; o[3 * j + 1] = l; o[3 * j + 2] = h;
    }
    u16* dst = outp + (size_t)row * K3 + c4 * 12;
#pragma unroll
    for (int j = 0; j < 3; ++j) *(ushort4*)(dst + 4 * j) = *(ushort4*)(o + 4 * j);
}

// ---------------- MFMA distance GEMM + running argmin ----------------
// grid (128, NSPLIT), block 256 = 4 waves in a 2x2 grid, 64x64 per wave
// (4x4 16x16x32 frags: 8 ds_read_b128 per 16 MFMA -- m97 fragment economics).
// Wave (wm,wn): rows [wm*64, wm*64+64) x cols [wn*64, wn*64+64) of the tile.
// Candidate set id = split*2 + wn  -> one writer per pi[set][row].
// LDS layout: [kblock(8)][row(128)][8 elems] -> conflict-free ds_read_b128.
__global__ __launch_bounds__(256, 2) void mfma_argmin_k(
    const short* __restrict__ x3, const short* __restrict__ e3,
    const float* __restrict__ knorm,
    int* __restrict__ pi1, int* __restrict__ pi2) {
    __shared__ __align__(16) short Abuf[8192];  // 16KB
    __shared__ __align__(16) short Bbuf[8192];  // 16KB

    const int tid  = threadIdx.x;
    const int lane = tid & 63;
    const int w    = tid >> 6;            // wave id 0..3
    const int wm   = w >> 1, wn = w & 1;
    const int g    = lane >> 4, r = lane & 15;
    const int rowBase  = blockIdx.x * 128;
    const int split    = blockIdx.y;
    const int colBase0 = split * (M / NSPLIT);

    float rv[16]; int ri[16];
#pragma unroll
    for (int s = 0; s < 16; ++s) { rv[s] = 3.0e38f; ri[s] = 0; }

#pragma unroll 1
    for (int nt = 0; nt < NTILES; ++nt) {
        const int colBase = colBase0 + nt * 128;
        f32x4 acc[4][4];
#pragma unroll
        for (int m = 0; m < 4; ++m)
#pragma unroll
            for (int n = 0; n < 4; ++n) acc[m][n] = (f32x4)(0.0f);

#pragma unroll 1
        for (int kt = 0; kt < K3 / 64; ++kt) {
            const int k0 = kt * 64;
            __syncthreads();
#pragma unroll
            for (int it = 0; it < 4; ++it) {
                int u = it * 256 + tid;
                int urow = u & 127, ukb = u >> 7;
                const short* as = x3 + (size_t)(rowBase + urow) * K3 + k0 + ukb * 8;
                const short* bs = e3 + (size_t)(colBase + urow) * K3 + k0 + ukb * 8;
                gl_lds16(as, &Abuf[u * 8]);
                gl_lds16(bs, &Bbuf[u * 8]);
            }
            __syncthreads();
#pragma unroll
            for (int ks = 0; ks < 2; ++ks) {
                s16x8 af[4], bfv[4];
#pragma unroll
                for (int m = 0; m < 4; ++m)
                    af[m] = *(const s16x8*)&Abuf[(((ks * 4 + g) * 128) + wm * 64 + m * 16 + r) * 8];
#pragma unroll
                for (int n = 0; n < 4; ++n)
                    bfv[n] = *(const s16x8*)&Bbuf[(((ks * 4 + g) * 128) + wn * 64 + n * 16 + r) * 8];
#pragma unroll
                for (int m = 0; m < 4; ++m)
#pragma unroll
                    for (int n = 0; n < 4; ++n)
                        acc[m][n] = __builtin_amdgcn_mfma_f32_16x16x32_bf16(
                            af[m], bfv[n], acc[m][n], 0, 0, 0);
            }
        }
        // epilogue: distances + running per-slot argmin (slot = (m,q))
#pragma unroll
        for (int n = 0; n < 4; ++n) {
            int col = colBase + wn * 64 + n * 16 + r;
            float kn = knorm[col];
#pragma unroll
            for (int m = 0; m < 4; ++m)
#pragma unroll
                for (int q = 0; q < 4; ++q) {
                    float d = fmaf(-2.0f, acc[m][n][q], kn);
                    int s = m * 4 + q;
                    if (d < rv[s]) { rv[s] = d; ri[s] = col; }
                }
        }
    }

    // cross-lane top-2 merge within 16-lane groups (lex order on (v, idx))
#pragma unroll
    for (int s = 0; s < 16; ++s) {
        float v1 = rv[s]; int i1 = ri[s];
        float v2 = 3.0e38f; int i2 = 0x7fffffff;
#pragma unroll
        for (int msk = 1; msk < 16; msk <<= 1) {
            float ov1 = __shfl_xor(v1, msk, 64);
            int   oi1 = __shfl_xor(i1, msk, 64);
            float ov2 = __shfl_xor(v2, msk, 64);
            int   oi2 = __shfl_xor(i2, msk, 64);
            bool ob = (ov1 < v1) || (ov1 == v1 && oi1 < i1);
            float nbv = ob ? ov1 : v1;  int nbi = ob ? oi1 : i1;
            float c1v = ob ? ov2 : v2;  int c1i = ob ? oi2 : i2;  // winner's own 2nd
            float c2v = ob ? v1 : ov1;  int c2i = ob ? i1 : oi1;  // loser's 1st
            bool cb = (c2v < c1v) || (c2v == c1v && c2i < c1i);
            v1 = nbv; i1 = nbi;
            v2 = cb ? c2v : c1v; i2 = cb ? c2i : c1i;
        }
        if (r == 0) {
            int row = rowBase + wm * 64 + (s >> 2) * 16 + g * 4 + (s & 3);
            int set = split * 2 + wn;
            pi1[(size_t)set * BNR + row] = i1;
            pi2[(size_t)set * BNR + row] = i2;
        }
    }
}

// ---------------- exact fp64 refine over 32 candidates/row ----------------
// block 256 = 4 waves = 4 rows; lane: cand c = lane&31, part p = lane>>5
__global__ void refine_k(const float* __restrict__ x, const float* __restrict__ emb,
                         const int* __restrict__ pi1, const int* __restrict__ pi2,
                         float* __restrict__ out_idx) {
    int row  = blockIdx.x * 4 + (threadIdx.x >> 6);
    int lane = threadIdx.x & 63;
    int c = lane & 31, p = lane >> 5;
    int cand = (c < NSETS) ? pi1[(size_t)c * BNR + row]
                           : pi2[(size_t)(c - NSETS) * BNR + row];
    const float4* qp = (const float4*)(x + (size_t)row * C);
    const float4* kp = (const float4*)(emb + (size_t)cand * C);
    double s = 0.0;
#pragma unroll 4
    for (int jj = 0; jj < 64; ++jj) {
        int j = p * 64 + jj;
        float4 q4 = qp[j], k4 = kp[j];
        double d0 = (double)q4.x - (double)k4.x;
        double d1 = (double)q4.y - (double)k4.y;
        double d2 = (double)q4.z - (double)k4.z;
        double d3 = (double)q4.w - (double)k4.w;
        s += d0 * d0 + d1 * d1 + d2 * d2 + d3 * d3;
    }
    s += __shfl_xor(s, 32, 64);
    double v = s; int bi = cand;
#pragma unroll
    for (int msk = 1; msk < 32; msk <<= 1) {
        double ov = __shfl_xor(v, msk, 64);
        int    oi = __shfl_xor(bi, msk, 64);
        if (ov < v || (ov == v && oi < bi)) { v = ov; bi = oi; }
    }
    if (lane == 0) out_idx[row] = (float)bi;
}

// ---------------- gather z_st + scatter onehot ones ----------------
__global__ void gather_k(const float* __restrict__ emb, const float* __restrict__ out_idx,
                         float* __restrict__ zst, float* __restrict__ onehot) {
    int row = blockIdx.x;
    int idx = (int)out_idx[row];
    const float4* src = (const float4*)(emb + (size_t)idx * C);
    float4* dst = (float4*)(zst + (size_t)row * C);
    dst[threadIdx.x] = src[threadIdx.x];
    if (threadIdx.x == 0) onehot[(size_t)row * M + idx] = 1.0f;
}

// ---------------- perplexity via LDS histogram ----------------
__global__ void perp_k(const float* __restrict__ out_idx, float* __restrict__ out_perp) {
    __shared__ int hist[M];
    __shared__ float red[256];
    int tid = threadIdx.x;
    for (int j = tid; j < M; j += 256) hist[j] = 0;
    __syncthreads();
    for (int j = tid; j < BNR; j += 256) atomicAdd(&hist[(int)out_idx[j]], 1);
    __syncthreads();
    float s = 0.f;
    for (int j = tid; j < M; j += 256) {
        float pb = (float)hist[j] * (1.0f / (float)BNR);
        s += pb * logf(pb + 1e-10f);
    }
    red[tid] = s; __syncthreads();
    for (int o = 128; o > 0; o >>= 1) {
        if (tid < o) red[tid] += red[tid + o];
        __syncthreads();
    }
    if (tid == 0) out_perp[0] = expf(-red[0]);
}

extern "C" void kernel_launch(void* const* d_in, const int* in_sizes, int n_in,
                              void* d_out, int out_size, void* d_ws, size_t ws_size,
                              hipStream_t stream) {
    const float* x   = (const float*)d_in[0];
    const float* emb = (const float*)d_in[1];

    float* out        = (float*)d_out;
    float* out_zst    = out;                              // 8388608
    float* out_idx    = out + (size_t)BNR * C;            // 16384
    float* out_onehot = out_idx + BNR;                    // 134217728
    float* out_perp   = out_onehot + (size_t)BNR * M;     // 1

    // scratch lives in the onehot region (memset afterwards)
    u16*   x3    = (u16*)out_onehot;                      // 48 MiB
    u16*   e3    = x3 + (size_t)BNR * K3;                 // 24 MiB
    float* knorm = (float*)(e3 + (size_t)M * K3);
    int*   pi1   = (int*)(knorm + M);
    int*   pi2   = pi1 + (size_t)NSETS * BNR;

    cvt_x_k<<<(BNR * C / 4) / 256, 256, 0, stream>>>(x, x3);
    cvt_e_k<<<(M * C / 4) / 256, 256, 0, stream>>>(emb, e3);
    knorm_k<<<64, 256, 0, stream>>>(emb, knorm);
    mfma_argmin_k<<<dim3(BNR / 128, NSPLIT), 256, 0, stream>>>(
        (const short*)x3, (const short*)e3, knorm, pi1, pi2);
    refine_k<<<BNR / 4, 256, 0, stream>>>(x, emb, pi1, pi2, out_idx);

    hipMemsetAsync(out_onehot, 0, (size_t)BNR * M * sizeof(float), stream);
    gather_k<<<BNR, 128, 0, stream>>>(emb, out_idx, out_zst, out_onehot);
    perp_k<<<1, 256, 0, stream>>>(out_idx, out_perp);
}

// Round 5
// 961.606 us; speedup vs baseline: 1.2849x; 1.2849x over previous
//
#include <hip/hip_runtime.h>
#include <cstdint>
#include <cstddef>

#define BNR 16384   // b*n rows
#define C   512     // feature dim
#define M   8192    // codebook size
#define K2  1024    // 2x expanded K: A={hi,lo}, B={hi,hi} (fp16 split)
#define BM  256
#define BN  256
#define BK  64
#define NSETS 32    // column blocks (8192/256)

typedef float f32x4 __attribute__((ext_vector_type(4)));
typedef _Float16 f16x8 __attribute__((ext_vector_type(8)));
typedef unsigned short u16;

static __device__ __forceinline__ u16 h_bits(_Float16 h) {
    union { _Float16 h; u16 u; } x; x.h = h; return x.u;
}
static __device__ __forceinline__ void gl_lds16(const void* g, void* l) {
    __builtin_amdgcn_global_load_lds(
        (const __attribute__((address_space(1))) void*)g,
        (__attribute__((address_space(3))) void*)l, 16, 0, 0);
}

// ---------------- ||k||^2 per codebook row (exact fp32) ----------------
__global__ void knorm_k(const float* __restrict__ emb, float* __restrict__ knorm) {
    int gw   = (blockIdx.x * blockDim.x + threadIdx.x) >> 6;
    int lane = threadIdx.x & 63;
    int nw   = (gridDim.x * blockDim.x) >> 6;
    for (int row = gw; row < M; row += nw) {
        const float4* p = (const float4*)(emb + (size_t)row * C);
        float s = 0.f;
#pragma unroll
        for (int j = 0; j < 2; ++j) {
            float4 v = p[lane + 64 * j];
            s += v.x * v.x + v.y * v.y + v.z * v.z + v.w * v.w;
        }
#pragma unroll
        for (int o = 32; o > 0; o >>= 1) s += __shfl_down(s, o, 64);
        if (lane == 0) knorm[row] = s;
    }
}

// ---------------- fp32 -> split-fp16 pairs ----------------
// x side: {hi, lo}
__global__ void cvt_x2_k(const float* __restrict__ in, u16* __restrict__ outp) {
    int t = blockIdx.x * 256 + threadIdx.x;     // one float4 per thread
    int row = t >> 7;                           // 128 float4 per row
    int c4  = t & 127;
    float4 v = *(const float4*)(in + ((size_t)row << 9) + c4 * 4);
    float e[4] = { v.x, v.y, v.z, v.w };
    u16 o[8];
#pragma unroll
    for (int j = 0; j < 4; ++j) {
        _Float16 h = (_Float16)e[j];
        _Float16 l = (_Float16)(e[j] - (float)h);
        o[2 * j] = h_bits(h); o[2 * j + 1] = h_bits(l);
    }
    u16* dst = outp + (size_t)row * K2 + c4 * 8;
    *(ushort4*)(dst)     = *(ushort4*)(o);
    *(ushort4*)(dst + 4) = *(ushort4*)(o + 4);
}
// emb side: {hi, hi}
__global__ void cvt_e2_k(const float* __restrict__ in, u16* __restrict__ outp) {
    int t = blockIdx.x * 256 + threadIdx.x;
    int row = t >> 7;
    int c4  = t & 127;
    float4 v = *(const float4*)(in + ((size_t)row << 9) + c4 * 4);
    float e[4] = { v.x, v.y, v.z, v.w };
    u16 o[8];
#pragma unroll
    for (int j = 0; j < 4; ++j) {
        u16 h = h_bits((_Float16)e[j]);
        o[2 * j] = h; o[2 * j + 1] = h;
    }
    u16* dst = outp + (size_t)row * K2 + c4 * 8;
    *(ushort4*)(dst)     = *(ushort4*)(o);
    *(ushort4*)(dst + 4) = *(ushort4*)(o + 4);
}

// ---------------- MFMA distance GEMM + per-colblock top-2 ----------------
// 2048 blocks x 512 threads. 8 waves (2M x 4N), per-wave 128x64 (acc[8][4]).
// Double-buffered LDS, prefetch chunk c+1 before computing chunk c,
// single barrier per chunk. LDS layout [buf][mat][kb][row][8]: conflict-free.
__global__ __launch_bounds__(512, 2) void mfma_argmin_k(
    const u16* __restrict__ x2, const u16* __restrict__ e2,
    const float* __restrict__ knorm,
    float* __restrict__ pv1, int* __restrict__ pi1,
    float* __restrict__ pv2, int* __restrict__ pi2) {
    __shared__ __align__(16) u16 lds[2][2][8][256][8];   // 128 KiB

    const int tid  = threadIdx.x;
    const int lane = tid & 63;
    const int w    = tid >> 6;          // 0..7
    const int wm   = w >> 2, wn = w & 3;
    const int g    = lane >> 4, r = lane & 15;

    // bijective XCD swizzle (2048 % 8 == 0), col-block slowest within XCD
    int wg = (blockIdx.x & 7) * 256 + (blockIdx.x >> 3);
    const int rb = wg & 63, cb = wg >> 6;
    const int rowBase = rb * BM, colBase = cb * BN;

    f32x4 acc[8][4];
#pragma unroll
    for (int m = 0; m < 8; ++m)
#pragma unroll
        for (int n = 0; n < 4; ++n) acc[m][n] = (f32x4)(0.0f);

    const u16* abase = x2 + (size_t)rowBase * K2;
    const u16* bbase = e2 + (size_t)colBase * K2;

#define STAGE(buf, c)                                                          \
    {                                                                          \
        _Pragma("unroll")                                                      \
        for (int it = 0; it < 4; ++it) {                                       \
            int u = it * 512 + tid;                                            \
            int urow = u & 255, ukb = u >> 8;                                  \
            gl_lds16(abase + (size_t)urow * K2 + (c) * BK + ukb * 8,           \
                     &lds[buf][0][ukb][urow][0]);                              \
            gl_lds16(bbase + (size_t)urow * K2 + (c) * BK + ukb * 8,           \
                     &lds[buf][1][ukb][urow][0]);                              \
        }                                                                      \
    }

    STAGE(0, 0);
    __syncthreads();

#pragma unroll 1
    for (int c = 0; c < K2 / BK; ++c) {
        const int buf = c & 1;
        if (c + 1 < K2 / BK) STAGE(buf ^ 1, c + 1);
#pragma unroll
        for (int ks = 0; ks < 2; ++ks) {
            const int kb = ks * 4 + g;
            f16x8 a[8], b[4];
#pragma unroll
            for (int m = 0; m < 8; ++m)
                a[m] = *(const f16x8*)&lds[buf][0][kb][wm * 128 + m * 16 + r][0];
#pragma unroll
            for (int n = 0; n < 4; ++n)
                b[n] = *(const f16x8*)&lds[buf][1][kb][wn * 64 + n * 16 + r][0];
#pragma unroll
            for (int m = 0; m < 8; ++m)
#pragma unroll
                for (int n = 0; n < 4; ++n)
                    acc[m][n] = __builtin_amdgcn_mfma_f32_16x16x32_f16(
                        a[m], b[n], acc[m][n], 0, 0, 0);
        }
        __syncthreads();
    }
#undef STAGE

    // ---- epilogue: per-row top-2 over this block's 256 cols ----
    float kn[4];
#pragma unroll
    for (int n = 0; n < 4; ++n) kn[n] = knorm[colBase + wn * 64 + n * 16 + r];

    // LDS reuse (safe: k-loop ended with __syncthreads)
    float* mv = (float*)&lds[0][0][0][0][0];      // [4 wn][256 row][2]
    int*   mi = (int*)(mv + 4 * 256 * 2);         // 8 KiB + 8 KiB

#pragma unroll
    for (int m = 0; m < 8; ++m) {
#pragma unroll
        for (int q = 0; q < 4; ++q) {
            float v1 = 3.0e38f, v2 = 3.0e38f;
            int   i1 = 0x7fffffff, i2 = 0x7fffffff;
#pragma unroll
            for (int n = 0; n < 4; ++n) {
                int col = colBase + wn * 64 + n * 16 + r;
                float d = fmaf(-2.0f, acc[m][n][q], kn[n]);
                if (d < v1 || (d == v1 && col < i1)) {
                    v2 = v1; i2 = i1; v1 = d; i1 = col;
                } else if (d < v2 || (d == v2 && col < i2)) {
                    v2 = d; i2 = col;
                }
            }
            // cross-lane top-2 merge over the 16 r-lanes
#pragma unroll
            for (int msk = 1; msk < 16; msk <<= 1) {
                float ov1 = __shfl_xor(v1, msk, 64);
                int   oi1 = __shfl_xor(i1, msk, 64);
                float ov2 = __shfl_xor(v2, msk, 64);
                int   oi2 = __shfl_xor(i2, msk, 64);
                bool ob = (ov1 < v1) || (ov1 == v1 && oi1 < i1);
                float nbv = ob ? ov1 : v1;  int nbi = ob ? oi1 : i1;
                float c1v = ob ? ov2 : v2;  int c1i = ob ? oi2 : i2;
                float c2v = ob ? v1 : ov1;  int c2i = ob ? i1 : oi1;
                bool cb2 = (c2v < c1v) || (c2v == c1v && c2i < c1i);
                v1 = nbv; i1 = nbi;
                v2 = cb2 ? c2v : c1v; i2 = cb2 ? c2i : c1i;
            }
            if (r == 0) {
                int lrow = wm * 128 + m * 16 + g * 4 + q;   // 0..255
                mv[(wn * 256 + lrow) * 2 + 0] = v1;
                mv[(wn * 256 + lrow) * 2 + 1] = v2;
                mi[(wn * 256 + lrow) * 2 + 0] = i1;
                mi[(wn * 256 + lrow) * 2 + 1] = i2;
            }
        }
    }
    __syncthreads();

    // merge 4 wn-waves' top-2 -> per-row top-2 over 256 cols
    if (tid < 256) {
        float V1 = 3.0e38f, V2 = 3.0e38f;
        int   I1 = 0x7fffffff, I2 = 0x7fffffff;
#pragma unroll
        for (int s = 0; s < 8; ++s) {
            float d = mv[((s >> 1) * 256 + tid) * 2 + (s & 1)];
            int   ci = mi[((s >> 1) * 256 + tid) * 2 + (s & 1)];
            if (d < V1 || (d == V1 && ci < I1)) {
                V2 = V1; I2 = I1; V1 = d; I1 = ci;
            } else if (d < V2 || (d == V2 && ci < I2)) {
                V2 = d; I2 = ci;
            }
        }
        size_t o = (size_t)cb * BNR + rowBase + tid;
        pv1[o] = V1; pi1[o] = I1;
        pv2[o] = V2; pi2[o] = I2;
    }
}

// ---------------- refine: top-8 by fp32 value, exact fp64 distances ----------------
// block 256 = 4 waves = 4 rows; 64 lanes hold 32 sets x {top1, top2}
__global__ void refine_k(const float* __restrict__ x, const float* __restrict__ emb,
                         const float* __restrict__ pv1, const int* __restrict__ pi1,
                         const float* __restrict__ pv2, const int* __restrict__ pi2,
                         float* __restrict__ out_idx) {
    int row  = blockIdx.x * 4 + (threadIdx.x >> 6);
    int lane = threadIdx.x & 63;
    float v; int idx;
    if (lane < NSETS) {
        v = pv1[(size_t)lane * BNR + row]; idx = pi1[(size_t)lane * BNR + row];
    } else {
        v = pv2[(size_t)(lane - NSETS) * BNR + row]; idx = pi2[(size_t)(lane - NSETS) * BNR + row];
    }
    // extract top-8 (lex on (v, idx)); all 64 entries are real candidates
    int cand[8];
#pragma unroll
    for (int b = 0; b < 8; ++b) {
        float mvv = v; int mii = idx;
#pragma unroll
        for (int msk = 1; msk < 64; msk <<= 1) {
            float ov = __shfl_xor(mvv, msk, 64);
            int   oi = __shfl_xor(mii, msk, 64);
            if (ov < mvv || (ov == mvv && oi < mii)) { mvv = ov; mii = oi; }
        }
        cand[b] = mii;
        if (v == mvv && idx == mii) { v = 3.0e38f; idx = 0x7fffffff; }
    }
    // 8 lanes per candidate: exact fp64 squared distance
    int gid = lane >> 3, gl = lane & 7;
    int myc = cand[gid];
    const float* qp = x + (size_t)row * C;
    const float* kp = emb + (size_t)myc * C;
    double s = 0.0;
#pragma unroll 4
    for (int j = gl * 64; j < gl * 64 + 64; j += 4) {
        float4 q4 = *(const float4*)(qp + j);
        float4 k4 = *(const float4*)(kp + j);
        double d0 = (double)q4.x - (double)k4.x;
        double d1 = (double)q4.y - (double)k4.y;
        double d2 = (double)q4.z - (double)k4.z;
        double d3 = (double)q4.w - (double)k4.w;
        s += d0 * d0 + d1 * d1 + d2 * d2 + d3 * d3;
    }
    s += __shfl_xor(s, 1, 64);
    s += __shfl_xor(s, 2, 64);
    s += __shfl_xor(s, 4, 64);
    double dv = (gl == 0) ? s : 1.0e300;
    int    di = (gl == 0) ? myc : 0x7fffffff;
#pragma unroll
    for (int msk = 8; msk < 64; msk <<= 1) {
        double ov = __shfl_xor(dv, msk, 64);
        int    oi = __shfl_xor(di, msk, 64);
        if (ov < dv || (ov == dv && oi < di)) { dv = ov; di = oi; }
    }
    if (lane == 0) out_idx[row] = (float)di;
}

// ---------------- gather z_st + scatter onehot ones ----------------
__global__ void gather_k(const float* __restrict__ emb, const float* __restrict__ out_idx,
                         float* __restrict__ zst, float* __restrict__ onehot) {
    int row = blockIdx.x;
    int idx = (int)out_idx[row];
    const float4* src = (const float4*)(emb + (size_t)idx * C);
    float4* dst = (float4*)(zst + (size_t)row * C);
    dst[threadIdx.x] = src[threadIdx.x];
    if (threadIdx.x == 0) onehot[(size_t)row * M + idx] = 1.0f;
}

// ---------------- perplexity via LDS histogram ----------------
__global__ void perp_k(const float* __restrict__ out_idx, float* __restrict__ out_perp) {
    __shared__ int hist[M];
    __shared__ float red[256];
    int tid = threadIdx.x;
    for (int j = tid; j < M; j += 256) hist[j] = 0;
    __syncthreads();
    for (int j = tid; j < BNR; j += 256) atomicAdd(&hist[(int)out_idx[j]], 1);
    __syncthreads();
    float s = 0.f;
    for (int j = tid; j < M; j += 256) {
        float pb = (float)hist[j] * (1.0f / (float)BNR);
        s += pb * logf(pb + 1e-10f);
    }
    red[tid] = s; __syncthreads();
    for (int o = 128; o > 0; o >>= 1) {
        if (tid < o) red[tid] += red[tid + o];
        __syncthreads();
    }
    if (tid == 0) out_perp[0] = expf(-red[0]);
}

extern "C" void kernel_launch(void* const* d_in, const int* in_sizes, int n_in,
                              void* d_out, int out_size, void* d_ws, size_t ws_size,
                              hipStream_t stream) {
    const float* x   = (const float*)d_in[0];
    const float* emb = (const float*)d_in[1];

    float* out        = (float*)d_out;
    float* out_zst    = out;                              // 8388608
    float* out_idx    = out + (size_t)BNR * C;            // 16384
    float* out_onehot = out_idx + BNR;                    // 134217728
    float* out_perp   = out_onehot + (size_t)BNR * M;     // 1

    // scratch lives in the onehot region (memset afterwards): ~60 MiB used
    u16*   x2    = (u16*)out_onehot;                      // 32 MiB
    u16*   e2    = x2 + (size_t)BNR * K2;                 // 16 MiB
    float* knorm = (float*)(e2 + (size_t)M * K2);
    float* pv1   = knorm + M;                             // 2 MiB each
    float* pv2   = pv1 + (size_t)NSETS * BNR;
    int*   pi1   = (int*)(pv2 + (size_t)NSETS * BNR);
    int*   pi2   = pi1 + (size_t)NSETS * BNR;

    cvt_x2_k<<<(BNR * C / 4) / 256, 256, 0, stream>>>(x, x2);
    cvt_e2_k<<<(M * C / 4) / 256, 256, 0, stream>>>(emb, e2);
    knorm_k<<<64, 256, 0, stream>>>(emb, knorm);
    mfma_argmin_k<<<(BNR / BM) * (M / BN), 512, 0, stream>>>(
        x2, e2, knorm, pv1, pi1, pv2, pi2);
    refine_k<<<BNR / 4, 256, 0, stream>>>(x, emb, pv1, pi1, pv2, pi2, out_idx);

    hipMemsetAsync(out_onehot, 0, (size_t)BNR * M * sizeof(float), stream);
    gather_k<<<BNR, 128, 0, stream>>>(emb, out_idx, out_zst, out_onehot);
    perp_k<<<1, 256, 0, stream>>>(out_idx, out_perp);
}

// Round 6
// 663.337 us; speedup vs baseline: 1.8626x; 1.4496x over previous
//
#include <hip/hip_runtime.h>
#include <cstdint>
#include <cstddef>

#define BNR 16384   // b*n rows
#define C   512     // feature dim
#define M   8192    // codebook size
#define BM  256
#define BN  256
#define BK  32
#define NCH 16      // K chunks = C/BK
#define NSETS 32    // column blocks (8192/256)

typedef float f32x4 __attribute__((ext_vector_type(4)));
typedef _Float16 f16x8 __attribute__((ext_vector_type(8)));
typedef unsigned short u16;

static __device__ __forceinline__ u16 h_bits(_Float16 h) {
    union { _Float16 h; u16 u; } x; x.h = h; return x.u;
}
static __device__ __forceinline__ void gl_lds16(const void* g, void* l) {
    __builtin_amdgcn_global_load_lds(
        (const __attribute__((address_space(1))) void*)g,
        (__attribute__((address_space(3))) void*)l, 16, 0, 0);
}

// ---------------- ||k||^2 per codebook row (exact fp32) ----------------
__global__ void knorm_k(const float* __restrict__ emb, float* __restrict__ knorm) {
    int gw   = (blockIdx.x * blockDim.x + threadIdx.x) >> 6;
    int lane = threadIdx.x & 63;
    int nw   = (gridDim.x * blockDim.x) >> 6;
    for (int row = gw; row < M; row += nw) {
        const float4* p = (const float4*)(emb + (size_t)row * C);
        float s = 0.f;
#pragma unroll
        for (int j = 0; j < 2; ++j) {
            float4 v = p[lane + 64 * j];
            s += v.x * v.x + v.y * v.y + v.z * v.z + v.w * v.w;
        }
#pragma unroll
        for (int o = 32; o > 0; o >>= 1) s += __shfl_down(s, o, 64);
        if (lane == 0) knorm[row] = s;
    }
}

// ---------------- fp32 -> fp16 (hi only), 8 elems/thread ----------------
__global__ void cvt_h_k(const float* __restrict__ in, u16* __restrict__ outp) {
    int t = blockIdx.x * 256 + threadIdx.x;
    const float4* p = (const float4*)in;
    float4 a = p[2 * t], b = p[2 * t + 1];
    u16 o[8] = { h_bits((_Float16)a.x), h_bits((_Float16)a.y),
                 h_bits((_Float16)a.z), h_bits((_Float16)a.w),
                 h_bits((_Float16)b.x), h_bits((_Float16)b.y),
                 h_bits((_Float16)b.z), h_bits((_Float16)b.w) };
    *(ushort4*)(outp + 8 * t)     = *(ushort4*)(o);
    *(ushort4*)(outp + 8 * t + 4) = *(ushort4*)(o + 4);
}

// ---------------- MFMA distance GEMM + per-colblock top-2 ----------------
// 2048 blocks x 512 threads (8 waves, 2M x 4N, per-wave 128x64 = acc[8][4]).
// 4-deep LDS ring (BK=32, 32 KiB/tile), stage tile c+3 each chunk,
// ONE raw s_barrier per chunk, counted s_waitcnt vmcnt(8) (drain-0 only in tail).
// LDS tile layout [kb(4)][row(256)][8] u16: conflict-free ds_read_b128.
__global__ __launch_bounds__(512, 2) void mfma_argmin_k(
    const u16* __restrict__ x2, const u16* __restrict__ e2,
    const float* __restrict__ knorm,
    float* __restrict__ pv1, int* __restrict__ pi1,
    float* __restrict__ pv2, int* __restrict__ pi2) {
    __shared__ __align__(16) u16 lds[4][2][4][256][8];   // 128 KiB

    const int tid  = threadIdx.x;
    const int lane = tid & 63;
    const int w    = tid >> 6;          // 0..7
    const int wm   = w >> 2, wn = w & 3;
    const int g    = lane >> 4, r = lane & 15;

    // supertile XCD swizzle: XCD gets 4 supertiles of 8rb x 8cb;
    // concurrent window (32 blocks) = 8 A-panels + 4 B-panels = 3 MiB <= L2.
    {
    }
    const int xk = blockIdx.x & 7, j = blockIdx.x >> 3;
    const int st = xk + 8 * (j >> 6);       // supertile 0..31
    const int p  = j & 63;
    const int rb = (st & 7) * 8 + (p & 7);  // 0..63
    const int cb = (st >> 3) * 8 + (p >> 3);// 0..31
    const int rowBase = rb * BM, colBase = cb * BN;

    f32x4 acc[8][4];
#pragma unroll
    for (int m = 0; m < 8; ++m)
#pragma unroll
        for (int n = 0; n < 4; ++n) acc[m][n] = (f32x4)(0.0f);

    const u16* abase = x2 + (size_t)rowBase * C;
    const u16* bbase = e2 + (size_t)colBase * C;

#define STAGE(buf, c)                                                          \
    {                                                                          \
        _Pragma("unroll")                                                      \
        for (int it = 0; it < 2; ++it) {                                       \
            int u = it * 512 + tid;                                            \
            int urow = u & 255, ukb = u >> 8;                                  \
            gl_lds16(abase + (size_t)urow * C + (c) * BK + ukb * 8,            \
                     &lds[buf][0][ukb][urow][0]);                              \
            gl_lds16(bbase + (size_t)urow * C + (c) * BK + ukb * 8,            \
                     &lds[buf][1][ukb][urow][0]);                              \
        }                                                                      \
    }

    // prologue: 3 tiles in flight (12 loads/thread)
    STAGE(0, 0);
    STAGE(1, 1);
    STAGE(2, 2);

#pragma unroll 1
    for (int c = 0; c < NCH; ++c) {
        // counted drain: T_c complete; keep up to 2 newer tiles in flight
        if (c <= NCH - 3)      asm volatile("s_waitcnt vmcnt(8)" ::: "memory");
        else if (c == NCH - 2) asm volatile("s_waitcnt vmcnt(4)" ::: "memory");
        else                   asm volatile("s_waitcnt vmcnt(0)" ::: "memory");
        __builtin_amdgcn_s_barrier();
        __builtin_amdgcn_sched_barrier(0);

        if (c + 3 < NCH) STAGE((c + 3) & 3, c + 3);   // ring slot free: readers done

        const int buf = c & 3;
        f16x8 a[8], b[4];
#pragma unroll
        for (int m = 0; m < 8; ++m)
            a[m] = *(const f16x8*)&lds[buf][0][g][wm * 128 + m * 16 + r][0];
#pragma unroll
        for (int n = 0; n < 4; ++n)
            b[n] = *(const f16x8*)&lds[buf][1][g][wn * 64 + n * 16 + r][0];

        __builtin_amdgcn_s_setprio(1);
#pragma unroll
        for (int m = 0; m < 8; ++m)
#pragma unroll
            for (int n = 0; n < 4; ++n)
                acc[m][n] = __builtin_amdgcn_mfma_f32_16x16x32_f16(
                    a[m], b[n], acc[m][n], 0, 0, 0);
        __builtin_amdgcn_s_setprio(0);
        __builtin_amdgcn_sched_barrier(0);
    }
#undef STAGE

    __syncthreads();   // full drain before LDS reuse

    // ---- epilogue: per-row top-2 over this block's 256 cols ----
    float kn[4];
#pragma unroll
    for (int n = 0; n < 4; ++n) kn[n] = knorm[colBase + wn * 64 + n * 16 + r];

    float* mv = (float*)&lds[0][0][0][0][0];      // [4 wn][256 row][2]
    int*   mi = (int*)(mv + 4 * 256 * 2);         // 8 KiB + 8 KiB

#pragma unroll
    for (int m = 0; m < 8; ++m) {
#pragma unroll
        for (int q = 0; q < 4; ++q) {
            float v1 = 3.0e38f, v2 = 3.0e38f;
            int   i1 = 0x7fffffff, i2 = 0x7fffffff;
#pragma unroll
            for (int n = 0; n < 4; ++n) {
                int col = colBase + wn * 64 + n * 16 + r;
                float d = fmaf(-2.0f, acc[m][n][q], kn[n]);
                if (d < v1 || (d == v1 && col < i1)) {
                    v2 = v1; i2 = i1; v1 = d; i1 = col;
                } else if (d < v2 || (d == v2 && col < i2)) {
                    v2 = d; i2 = col;
                }
            }
#pragma unroll
            for (int msk = 1; msk < 16; msk <<= 1) {
                float ov1 = __shfl_xor(v1, msk, 64);
                int   oi1 = __shfl_xor(i1, msk, 64);
                float ov2 = __shfl_xor(v2, msk, 64);
                int   oi2 = __shfl_xor(i2, msk, 64);
                bool ob = (ov1 < v1) || (ov1 == v1 && oi1 < i1);
                float nbv = ob ? ov1 : v1;  int nbi = ob ? oi1 : i1;
                float c1v = ob ? ov2 : v2;  int c1i = ob ? oi2 : i2;
                float c2v = ob ? v1 : ov1;  int c2i = ob ? i1 : oi1;
                bool cb2 = (c2v < c1v) || (c2v == c1v && c2i < c1i);
                v1 = nbv; i1 = nbi;
                v2 = cb2 ? c2v : c1v; i2 = cb2 ? c2i : c1i;
            }
            if (r == 0) {
                int lrow = wm * 128 + m * 16 + g * 4 + q;   // 0..255
                mv[(wn * 256 + lrow) * 2 + 0] = v1;
                mv[(wn * 256 + lrow) * 2 + 1] = v2;
                mi[(wn * 256 + lrow) * 2 + 0] = i1;
                mi[(wn * 256 + lrow) * 2 + 1] = i2;
            }
        }
    }
    __syncthreads();

    // merge 4 wn-waves' top-2 -> per-row top-2 over 256 cols
    if (tid < 256) {
        float V1 = 3.0e38f, V2 = 3.0e38f;
        int   I1 = 0x7fffffff, I2 = 0x7fffffff;
#pragma unroll
        for (int s = 0; s < 8; ++s) {
            float d = mv[((s >> 1) * 256 + tid) * 2 + (s & 1)];
            int   ci = mi[((s >> 1) * 256 + tid) * 2 + (s & 1)];
            if (d < V1 || (d == V1 && ci < I1)) {
                V2 = V1; I2 = I1; V1 = d; I1 = ci;
            } else if (d < V2 || (d == V2 && ci < I2)) {
                V2 = d; I2 = ci;
            }
        }
        size_t o = (size_t)cb * BNR + rowBase + tid;
        pv1[o] = V1; pi1[o] = I1;
        pv2[o] = V2; pi2[o] = I2;
    }
}

// ---------------- refine: top-8 by fp32 value, exact fp64 distances ----------------
__global__ void refine_k(const float* __restrict__ x, const float* __restrict__ emb,
                         const float* __restrict__ pv1, const int* __restrict__ pi1,
                         const float* __restrict__ pv2, const int* __restrict__ pi2,
                         float* __restrict__ out_idx) {
    int row  = blockIdx.x * 4 + (threadIdx.x >> 6);
    int lane = threadIdx.x & 63;
    float v; int idx;
    if (lane < NSETS) {
        v = pv1[(size_t)lane * BNR + row]; idx = pi1[(size_t)lane * BNR + row];
    } else {
        v = pv2[(size_t)(lane - NSETS) * BNR + row]; idx = pi2[(size_t)(lane - NSETS) * BNR + row];
    }
    int cand[8];
#pragma unroll
    for (int b = 0; b < 8; ++b) {
        float mvv = v; int mii = idx;
#pragma unroll
        for (int msk = 1; msk < 64; msk <<= 1) {
            float ov = __shfl_xor(mvv, msk, 64);
            int   oi = __shfl_xor(mii, msk, 64);
            if (ov < mvv || (ov == mvv && oi < mii)) { mvv = ov; mii = oi; }
        }
        cand[b] = mii;
        if (v == mvv && idx == mii) { v = 3.0e38f; idx = 0x7fffffff; }
    }
    int gid = lane >> 3, gl = lane & 7;
    int myc = cand[gid];
    const float* qp = x + (size_t)row * C;
    const float* kp = emb + (size_t)myc * C;
    double s = 0.0;
#pragma unroll 4
    for (int j = gl * 64; j < gl * 64 + 64; j += 4) {
        float4 q4 = *(const float4*)(qp + j);
        float4 k4 = *(const float4*)(kp + j);
        double d0 = (double)q4.x - (double)k4.x;
        double d1 = (double)q4.y - (double)k4.y;
        double d2 = (double)q4.z - (double)k4.z;
        double d3 = (double)q4.w - (double)k4.w;
        s += d0 * d0 + d1 * d1 + d2 * d2 + d3 * d3;
    }
    s += __shfl_xor(s, 1, 64);
    s += __shfl_xor(s, 2, 64);
    s += __shfl_xor(s, 4, 64);
    double dv = (gl == 0) ? s : 1.0e300;
    int    di = (gl == 0) ? myc : 0x7fffffff;
#pragma unroll
    for (int msk = 8; msk < 64; msk <<= 1) {
        double ov = __shfl_xor(dv, msk, 64);
        int    oi = __shfl_xor(di, msk, 64);
        if (ov < dv || (ov == dv && oi < di)) { dv = ov; di = oi; }
    }
    if (lane == 0) out_idx[row] = (float)di;
}

// ---------------- gather z_st + scatter onehot ones ----------------
__global__ void gather_k(const float* __restrict__ emb, const float* __restrict__ out_idx,
                         float* __restrict__ zst, float* __restrict__ onehot) {
    int row = blockIdx.x;
    int idx = (int)out_idx[row];
    const float4* src = (const float4*)(emb + (size_t)idx * C);
    float4* dst = (float4*)(zst + (size_t)row * C);
    dst[threadIdx.x] = src[threadIdx.x];
    if (threadIdx.x == 0) onehot[(size_t)row * M + idx] = 1.0f;
}

// ---------------- perplexity via LDS histogram ----------------
__global__ void perp_k(const float* __restrict__ out_idx, float* __restrict__ out_perp) {
    __shared__ int hist[M];
    __shared__ float red[256];
    int tid = threadIdx.x;
    for (int j = tid; j < M; j += 256) hist[j] = 0;
    __syncthreads();
    for (int j = tid; j < BNR; j += 256) atomicAdd(&hist[(int)out_idx[j]], 1);
    __syncthreads();
    float s = 0.f;
    for (int j = tid; j < M; j += 256) {
        float pb = (float)hist[j] * (1.0f / (float)BNR);
        s += pb * logf(pb + 1e-10f);
    }
    red[tid] = s; __syncthreads();
    for (int o = 128; o > 0; o >>= 1) {
        if (tid < o) red[tid] += red[tid + o];
        __syncthreads();
    }
    if (tid == 0) out_perp[0] = expf(-red[0]);
}

extern "C" void kernel_launch(void* const* d_in, const int* in_sizes, int n_in,
                              void* d_out, int out_size, void* d_ws, size_t ws_size,
                              hipStream_t stream) {
    const float* x   = (const float*)d_in[0];
    const float* emb = (const float*)d_in[1];

    float* out        = (float*)d_out;
    float* out_zst    = out;                              // 8388608
    float* out_idx    = out + (size_t)BNR * C;            // 16384
    float* out_onehot = out_idx + BNR;                    // 134217728
    float* out_perp   = out_onehot + (size_t)BNR * M;     // 1

    // scratch lives in the onehot region (memset afterwards): ~34 MiB used
    u16*   x2    = (u16*)out_onehot;                      // 16 MiB
    u16*   e2    = x2 + (size_t)BNR * C;                  // 8 MiB
    float* knorm = (float*)(e2 + (size_t)M * C);
    float* pv1   = knorm + M;
    float* pv2   = pv1 + (size_t)NSETS * BNR;
    int*   pi1   = (int*)(pv2 + (size_t)NSETS * BNR);
    int*   pi2   = pi1 + (size_t)NSETS * BNR;

    cvt_h_k<<<(BNR * C / 8) / 256, 256, 0, stream>>>(x, x2);
    cvt_h_k<<<(M * C / 8) / 256, 256, 0, stream>>>(emb, e2);
    knorm_k<<<64, 256, 0, stream>>>(emb, knorm);
    mfma_argmin_k<<<(BNR / BM) * (M / BN), 512, 0, stream>>>(
        x2, e2, knorm, pv1, pi1, pv2, pi2);
    refine_k<<<BNR / 4, 256, 0, stream>>>(x, emb, pv1, pi1, pv2, pi2, out_idx);

    hipMemsetAsync(out_onehot, 0, (size_t)BNR * M * sizeof(float), stream);
    gather_k<<<BNR, 128, 0, stream>>>(emb, out_idx, out_zst, out_onehot);
    perp_k<<<1, 256, 0, stream>>>(out_idx, out_perp);
}

// Round 7
// 662.171 us; speedup vs baseline: 1.8659x; 1.0018x over previous
//
#include <hip/hip_runtime.h>
#include <cstdint>
#include <cstddef>

#define BNR 16384   // b*n rows
#define C   512     // feature dim
#define M   8192    // codebook size
#define BM  256
#define BN  256
#define BK  32
#define NCH 16      // K chunks = C/BK
#define NSETS 32    // column blocks (8192/256)

typedef float f32x4 __attribute__((ext_vector_type(4)));
typedef _Float16 f16x8 __attribute__((ext_vector_type(8)));
typedef unsigned short u16;

static __device__ __forceinline__ u16 h_bits(_Float16 h) {
    union { _Float16 h; u16 u; } x; x.h = h; return x.u;
}
static __device__ __forceinline__ void gl_lds16(const void* g, void* l) {
    __builtin_amdgcn_global_load_lds(
        (const __attribute__((address_space(1))) void*)g,
        (__attribute__((address_space(3))) void*)l, 16, 0, 0);
}

// ---------------- ||k||^2 per codebook row (exact fp32) ----------------
__global__ void knorm_k(const float* __restrict__ emb, float* __restrict__ knorm) {
    int gw   = (blockIdx.x * blockDim.x + threadIdx.x) >> 6;
    int lane = threadIdx.x & 63;
    int nw   = (gridDim.x * blockDim.x) >> 6;
    for (int row = gw; row < M; row += nw) {
        const float4* p = (const float4*)(emb + (size_t)row * C);
        float s = 0.f;
#pragma unroll
        for (int j = 0; j < 2; ++j) {
            float4 v = p[lane + 64 * j];
            s += v.x * v.x + v.y * v.y + v.z * v.z + v.w * v.w;
        }
#pragma unroll
        for (int o = 32; o > 0; o >>= 1) s += __shfl_down(s, o, 64);
        if (lane == 0) knorm[row] = s;
    }
}

// ---------------- fp32 -> fp16 (hi only), 8 elems/thread ----------------
__global__ void cvt_h_k(const float* __restrict__ in, u16* __restrict__ outp) {
    int t = blockIdx.x * 256 + threadIdx.x;
    const float4* p = (const float4*)in;
    float4 a = p[2 * t], b = p[2 * t + 1];
    u16 o[8] = { h_bits((_Float16)a.x), h_bits((_Float16)a.y),
                 h_bits((_Float16)a.z), h_bits((_Float16)a.w),
                 h_bits((_Float16)b.x), h_bits((_Float16)b.y),
                 h_bits((_Float16)b.z), h_bits((_Float16)b.w) };
    *(ushort4*)(outp + 8 * t)     = *(ushort4*)(o);
    *(ushort4*)(outp + 8 * t + 4) = *(ushort4*)(o + 4);
}

// ---------------- MFMA distance GEMM + per-colblock top-2 ----------------
// 2048 blocks x 512 threads (8 waves, 2M x 4N, per-wave 128x64 = acc[8][4]).
// 4-deep LDS ring (BK=32, 32 KiB/tile), stage tile c+3 each chunk,
// ONE raw s_barrier per chunk, counted s_waitcnt vmcnt(8) (drain-0 only in tail).
// LDS tile layout [kb(4)][row(256)][8] u16: conflict-free ds_read_b128.
__global__ __launch_bounds__(512, 2) void mfma_argmin_k(
    const u16* __restrict__ x2, const u16* __restrict__ e2,
    const float* __restrict__ knorm,
    float* __restrict__ pv1, int* __restrict__ pi1,
    float* __restrict__ pv2, int* __restrict__ pi2) {
    __shared__ __align__(16) u16 lds[4][2][4][256][8];   // 128 KiB

    const int tid  = threadIdx.x;
    const int lane = tid & 63;
    const int w    = tid >> 6;          // 0..7
    const int wm   = w >> 2, wn = w & 3;
    const int g    = lane >> 4, r = lane & 15;

    // supertile XCD swizzle: XCD gets 4 supertiles of 8rb x 8cb;
    // concurrent window (32 blocks) = 8 A-panels + 4 B-panels = 3 MiB <= L2.
    {
    }
    const int xk = blockIdx.x & 7, j = blockIdx.x >> 3;
    const int st = xk + 8 * (j >> 6);       // supertile 0..31
    const int p  = j & 63;
    const int rb = (st & 7) * 8 + (p & 7);  // 0..63
    const int cb = (st >> 3) * 8 + (p >> 3);// 0..31
    const int rowBase = rb * BM, colBase = cb * BN;

    f32x4 acc[8][4];
#pragma unroll
    for (int m = 0; m < 8; ++m)
#pragma unroll
        for (int n = 0; n < 4; ++n) acc[m][n] = (f32x4)(0.0f);

    const u16* abase = x2 + (size_t)rowBase * C;
    const u16* bbase = e2 + (size_t)colBase * C;

#define STAGE(buf, c)                                                          \
    {                                                                          \
        _Pragma("unroll")                                                      \
        for (int it = 0; it < 2; ++it) {                                       \
            int u = it * 512 + tid;                                            \
            int urow = u & 255, ukb = u >> 8;                                  \
            gl_lds16(abase + (size_t)urow * C + (c) * BK + ukb * 8,            \
                     &lds[buf][0][ukb][urow][0]);                              \
            gl_lds16(bbase + (size_t)urow * C + (c) * BK + ukb * 8,            \
                     &lds[buf][1][ukb][urow][0]);                              \
        }                                                                      \
    }

    // prologue: 3 tiles in flight (12 loads/thread)
    STAGE(0, 0);
    STAGE(1, 1);
    STAGE(2, 2);

#pragma unroll 1
    for (int c = 0; c < NCH; ++c) {
        // counted drain: T_c complete; keep up to 2 newer tiles in flight
        if (c <= NCH - 3)      asm volatile("s_waitcnt vmcnt(8)" ::: "memory");
        else if (c == NCH - 2) asm volatile("s_waitcnt vmcnt(4)" ::: "memory");
        else                   asm volatile("s_waitcnt vmcnt(0)" ::: "memory");
        __builtin_amdgcn_s_barrier();
        __builtin_amdgcn_sched_barrier(0);

        if (c + 3 < NCH) STAGE((c + 3) & 3, c + 3);   // ring slot free: readers done

        const int buf = c & 3;
        f16x8 a[8], b[4];
#pragma unroll
        for (int m = 0; m < 8; ++m)
            a[m] = *(const f16x8*)&lds[buf][0][g][wm * 128 + m * 16 + r][0];
#pragma unroll
        for (int n = 0; n < 4; ++n)
            b[n] = *(const f16x8*)&lds[buf][1][g][wn * 64 + n * 16 + r][0];

        __builtin_amdgcn_s_setprio(1);
#pragma unroll
        for (int m = 0; m < 8; ++m)
#pragma unroll
            for (int n = 0; n < 4; ++n)
                acc[m][n] = __builtin_amdgcn_mfma_f32_16x16x32_f16(
                    a[m], b[n], acc[m][n], 0, 0, 0);
        __builtin_amdgcn_s_setprio(0);
        __builtin_amdgcn_sched_barrier(0);
    }
#undef STAGE

    __syncthreads();   // full drain before LDS reuse

    // ---- epilogue: per-row top-2 over this block's 256 cols ----
    float kn[4];
#pragma unroll
    for (int n = 0; n < 4; ++n) kn[n] = knorm[colBase + wn * 64 + n * 16 + r];

    float* mv = (float*)&lds[0][0][0][0][0];      // [4 wn][256 row][2]
    int*   mi = (int*)(mv + 4 * 256 * 2);         // 8 KiB + 8 KiB

#pragma unroll
    for (int m = 0; m < 8; ++m) {
#pragma unroll
        for (int q = 0; q < 4; ++q) {
            float v1 = 3.0e38f, v2 = 3.0e38f;
            int   i1 = 0x7fffffff, i2 = 0x7fffffff;
#pragma unroll
            for (int n = 0; n < 4; ++n) {
                int col = colBase + wn * 64 + n * 16 + r;
                float d = fmaf(-2.0f, acc[m][n][q], kn[n]);
                if (d < v1 || (d == v1 && col < i1)) {
                    v2 = v1; i2 = i1; v1 = d; i1 = col;
                } else if (d < v2 || (d == v2 && col < i2)) {
                    v2 = d; i2 = col;
                }
            }
#pragma unroll
            for (int msk = 1; msk < 16; msk <<= 1) {
                float ov1 = __shfl_xor(v1, msk, 64);
                int   oi1 = __shfl_xor(i1, msk, 64);
                float ov2 = __shfl_xor(v2, msk, 64);
                int   oi2 = __shfl_xor(i2, msk, 64);
                bool ob = (ov1 < v1) || (ov1 == v1 && oi1 < i1);
                float nbv = ob ? ov1 : v1;  int nbi = ob ? oi1 : i1;
                float c1v = ob ? ov2 : v2;  int c1i = ob ? oi2 : i2;
                float c2v = ob ? v1 : ov1;  int c2i = ob ? i1 : oi1;
                bool cb2 = (c2v < c1v) || (c2v == c1v && c2i < c1i);
                v1 = nbv; i1 = nbi;
                v2 = cb2 ? c2v : c1v; i2 = cb2 ? c2i : c1i;
            }
            if (r == 0) {
                int lrow = wm * 128 + m * 16 + g * 4 + q;   // 0..255
                mv[(wn * 256 + lrow) * 2 + 0] = v1;
                mv[(wn * 256 + lrow) * 2 + 1] = v2;
                mi[(wn * 256 + lrow) * 2 + 0] = i1;
                mi[(wn * 256 + lrow) * 2 + 1] = i2;
            }
        }
    }
    __syncthreads();

    // merge 4 wn-waves' top-2 -> per-row top-2 over 256 cols
    if (tid < 256) {
        float V1 = 3.0e38f, V2 = 3.0e38f;
        int   I1 = 0x7fffffff, I2 = 0x7fffffff;
#pragma unroll
        for (int s = 0; s < 8; ++s) {
            float d = mv[((s >> 1) * 256 + tid) * 2 + (s & 1)];
            int   ci = mi[((s >> 1) * 256 + tid) * 2 + (s & 1)];
            if (d < V1 || (d == V1 && ci < I1)) {
                V2 = V1; I2 = I1; V1 = d; I1 = ci;
            } else if (d < V2 || (d == V2 && ci < I2)) {
                V2 = d; I2 = ci;
            }
        }
        size_t o = (size_t)cb * BNR + rowBase + tid;
        pv1[o] = V1; pi1[o] = I1;
        pv2[o] = V2; pi2[o] = I2;
    }
}

// ---------------- refine: top-8 by fp32 value, exact fp64 distances ----------------
__global__ void refine_k(const float* __restrict__ x, const float* __restrict__ emb,
                         const float* __restrict__ pv1, const int* __restrict__ pi1,
                         const float* __restrict__ pv2, const int* __restrict__ pi2,
                         float* __restrict__ out_idx) {
    int row  = blockIdx.x * 4 + (threadIdx.x >> 6);
    int lane = threadIdx.x & 63;
    float v; int idx;
    if (lane < NSETS) {
        v = pv1[(size_t)lane * BNR + row]; idx = pi1[(size_t)lane * BNR + row];
    } else {
        v = pv2[(size_t)(lane - NSETS) * BNR + row]; idx = pi2[(size_t)(lane - NSETS) * BNR + row];
    }
    int cand[8];
#pragma unroll
    for (int b = 0; b < 8; ++b) {
        float mvv = v; int mii = idx;
#pragma unroll
        for (int msk = 1; msk < 64; msk <<= 1) {
            float ov = __shfl_xor(mvv, msk, 64);
            int   oi = __shfl_xor(mii, msk, 64);
            if (ov < mvv || (ov == mvv && oi < mii)) { mvv = ov; mii = oi; }
        }
        cand[b] = mii;
        if (v == mvv && idx == mii) { v = 3.0e38f; idx = 0x7fffffff; }
    }
    int gid = lane >> 3, gl = lane & 7;
    int myc = cand[gid];
    const float* qp = x + (size_t)row * C;
    const float* kp = emb + (size_t)myc * C;
    double s = 0.0;
#pragma unroll 4
    for (int j = gl * 64; j < gl * 64 + 64; j += 4) {
        float4 q4 = *(const float4*)(qp + j);
        float4 k4 = *(const float4*)(kp + j);
        double d0 = (double)q4.x - (double)k4.x;
        double d1 = (double)q4.y - (double)k4.y;
        double d2 = (double)q4.z - (double)k4.z;
        double d3 = (double)q4.w - (double)k4.w;
        s += d0 * d0 + d1 * d1 + d2 * d2 + d3 * d3;
    }
    s += __shfl_xor(s, 1, 64);
    s += __shfl_xor(s, 2, 64);
    s += __shfl_xor(s, 4, 64);
    double dv = (gl == 0) ? s : 1.0e300;
    int    di = (gl == 0) ? myc : 0x7fffffff;
#pragma unroll
    for (int msk = 8; msk < 64; msk <<= 1) {
        double ov = __shfl_xor(dv, msk, 64);
        int    oi = __shfl_xor(di, msk, 64);
        if (ov < dv || (ov == dv && oi < di)) { dv = ov; di = oi; }
    }
    if (lane == 0) out_idx[row] = (float)di;
}

// ---------------- gather z_st + scatter onehot ones ----------------
__global__ void gather_k(const float* __restrict__ emb, const float* __restrict__ out_idx,
                         float* __restrict__ zst, float* __restrict__ onehot) {
    int row = blockIdx.x;
    int idx = (int)out_idx[row];
    const float4* src = (const float4*)(emb + (size_t)idx * C);
    float4* dst = (float4*)(zst + (size_t)row * C);
    dst[threadIdx.x] = src[threadIdx.x];
    if (threadIdx.x == 0) onehot[(size_t)row * M + idx] = 1.0f;
}

// ---------------- perplexity via LDS histogram ----------------
__global__ void perp_k(const float* __restrict__ out_idx, float* __restrict__ out_perp) {
    __shared__ int hist[M];
    __shared__ float red[256];
    int tid = threadIdx.x;
    for (int j = tid; j < M; j += 256) hist[j] = 0;
    __syncthreads();
    for (int j = tid; j < BNR; j += 256) atomicAdd(&hist[(int)out_idx[j]], 1);
    __syncthreads();
    float s = 0.f;
    for (int j = tid; j < M; j += 256) {
        float pb = (float)hist[j] * (1.0f / (float)BNR);
        s += pb * logf(pb + 1e-10f);
    }
    red[tid] = s; __syncthreads();
    for (int o = 128; o > 0; o >>= 1) {
        if (tid < o) red[tid] += red[tid + o];
        __syncthreads();
    }
    if (tid == 0) out_perp[0] = expf(-red[0]);
}

extern "C" void kernel_launch(void* const* d_in, const int* in_sizes, int n_in,
                              void* d_out, int out_size, void* d_ws, size_t ws_size,
                              hipStream_t stream) {
    const float* x   = (const float*)d_in[0];
    const float* emb = (const float*)d_in[1];

    float* out        = (float*)d_out;
    float* out_zst    = out;                              // 8388608
    float* out_idx    = out + (size_t)BNR * C;            // 16384
    float* out_onehot = out_idx + BNR;                    // 134217728
    float* out_perp   = out_onehot + (size_t)BNR * M;     // 1

    // scratch lives in the onehot region (memset afterwards): ~34 MiB used
    u16*   x2    = (u16*)out_onehot;                      // 16 MiB
    u16*   e2    = x2 + (size_t)BNR * C;                  // 8 MiB
    float* knorm = (float*)(e2 + (size_t)M * C);
    float* pv1   = knorm + M;
    float* pv2   = pv1 + (size_t)NSETS * BNR;
    int*   pi1   = (int*)(pv2 + (size_t)NSETS * BNR);
    int*   pi2   = pi1 + (size_t)NSETS * BNR;

    cvt_h_k<<<(BNR * C / 8) / 256, 256, 0, stream>>>(x, x2);
    cvt_h_k<<<(M * C / 8) / 256, 256, 0, stream>>>(emb, e2);
    knorm_k<<<64, 256, 0, stream>>>(emb, knorm);
    mfma_argmin_k<<<(BNR / BM) * (M / BN), 512, 0, stream>>>(
        x2, e2, knorm, pv1, pi1, pv2, pi2);
    refine_k<<<BNR / 4, 256, 0, stream>>>(x, emb, pv1, pi1, pv2, pi2, out_idx);

    hipMemsetAsync(out_onehot, 0, (size_t)BNR * M * sizeof(float), stream);
    gather_k<<<BNR, 128, 0, stream>>>(emb, out_idx, out_zst, out_onehot);
    perp_k<<<1, 256, 0, stream>>>(out_idx, out_perp);
}

// Round 8
// 661.701 us; speedup vs baseline: 1.8672x; 1.0007x over previous
//
#include <hip/hip_runtime.h>
#include <cstdint>
#include <cstddef>

#define BNR 16384   // b*n rows
#define C   512     // feature dim
#define M   8192    // codebook size
#define BM  256
#define BN  256
#define BK  32
#define NCH 16      // K chunks = C/BK
#define NSETS 32    // column blocks (8192/256)

typedef float f32x4 __attribute__((ext_vector_type(4)));
typedef _Float16 f16x8 __attribute__((ext_vector_type(8)));
typedef unsigned short u16;

static __device__ __forceinline__ u16 h_bits(_Float16 h) {
    union { _Float16 h; u16 u; } x; x.h = h; return x.u;
}
static __device__ __forceinline__ void gl_lds16(const void* g, void* l) {
    __builtin_amdgcn_global_load_lds(
        (const __attribute__((address_space(1))) void*)g,
        (__attribute__((address_space(3))) void*)l, 16, 0, 0);
}

// ---------------- ||k||^2 per codebook row (exact fp32) ----------------
__global__ void knorm_k(const float* __restrict__ emb, float* __restrict__ knorm) {
    int gw   = (blockIdx.x * blockDim.x + threadIdx.x) >> 6;
    int lane = threadIdx.x & 63;
    int nw   = (gridDim.x * blockDim.x) >> 6;
    for (int row = gw; row < M; row += nw) {
        const float4* p = (const float4*)(emb + (size_t)row * C);
        float s = 0.f;
#pragma unroll
        for (int j = 0; j < 2; ++j) {
            float4 v = p[lane + 64 * j];
            s += v.x * v.x + v.y * v.y + v.z * v.z + v.w * v.w;
        }
#pragma unroll
        for (int o = 32; o > 0; o >>= 1) s += __shfl_down(s, o, 64);
        if (lane == 0) knorm[row] = s;
    }
}

// ---------------- fp32 -> fp16 (hi only), 8 elems/thread ----------------
__global__ void cvt_h_k(const float* __restrict__ in, u16* __restrict__ outp) {
    int t = blockIdx.x * 256 + threadIdx.x;
    const float4* p = (const float4*)in;
    float4 a = p[2 * t], b = p[2 * t + 1];
    u16 o[8] = { h_bits((_Float16)a.x), h_bits((_Float16)a.y),
                 h_bits((_Float16)a.z), h_bits((_Float16)a.w),
                 h_bits((_Float16)b.x), h_bits((_Float16)b.y),
                 h_bits((_Float16)b.z), h_bits((_Float16)b.w) };
    *(ushort4*)(outp + 8 * t)     = *(ushort4*)(o);
    *(ushort4*)(outp + 8 * t + 4) = *(ushort4*)(o + 4);
}

// ---------------- MFMA distance GEMM + per-colblock top-2 ----------------
// 2048 blocks x 512 threads (8 waves, 2M x 4N, per-wave 128x64 = acc[8][4]).
// 4-deep LDS ring (BK=32, 32 KiB/tile), stage tile c+3 each chunk,
// ONE raw s_barrier per chunk, counted s_waitcnt vmcnt(8) (drain-0 only in tail).
// LDS tile layout [kb(4)][row(256)][8] u16: conflict-free ds_read_b128.
__global__ __launch_bounds__(512, 2) void mfma_argmin_k(
    const u16* __restrict__ x2, const u16* __restrict__ e2,
    const float* __restrict__ knorm,
    float* __restrict__ pv1, int* __restrict__ pi1,
    float* __restrict__ pv2, int* __restrict__ pi2) {
    __shared__ __align__(16) u16 lds[4][2][4][256][8];   // 128 KiB

    const int tid  = threadIdx.x;
    const int lane = tid & 63;
    const int w    = tid >> 6;          // 0..7
    const int wm   = w >> 2, wn = w & 3;
    const int g    = lane >> 4, r = lane & 15;

    // supertile XCD swizzle: XCD gets 4 supertiles of 8rb x 8cb;
    // concurrent window (32 blocks) = 8 A-panels + 4 B-panels = 3 MiB <= L2.
    {
    }
    const int xk = blockIdx.x & 7, j = blockIdx.x >> 3;
    const int st = xk + 8 * (j >> 6);       // supertile 0..31
    const int p  = j & 63;
    const int rb = (st & 7) * 8 + (p & 7);  // 0..63
    const int cb = (st >> 3) * 8 + (p >> 3);// 0..31
    const int rowBase = rb * BM, colBase = cb * BN;

    f32x4 acc[8][4];
#pragma unroll
    for (int m = 0; m < 8; ++m)
#pragma unroll
        for (int n = 0; n < 4; ++n) acc[m][n] = (f32x4)(0.0f);

    const u16* abase = x2 + (size_t)rowBase * C;
    const u16* bbase = e2 + (size_t)colBase * C;

#define STAGE(buf, c)                                                          \
    {                                                                          \
        _Pragma("unroll")                                                      \
        for (int it = 0; it < 2; ++it) {                                       \
            int u = it * 512 + tid;                                            \
            int urow = u & 255, ukb = u >> 8;                                  \
            gl_lds16(abase + (size_t)urow * C + (c) * BK + ukb * 8,            \
                     &lds[buf][0][ukb][urow][0]);                              \
            gl_lds16(bbase + (size_t)urow * C + (c) * BK + ukb * 8,            \
                     &lds[buf][1][ukb][urow][0]);                              \
        }                                                                      \
    }

    // prologue: 3 tiles in flight (12 loads/thread)
    STAGE(0, 0);
    STAGE(1, 1);
    STAGE(2, 2);

#pragma unroll 1
    for (int c = 0; c < NCH; ++c) {
        // counted drain: T_c complete; keep up to 2 newer tiles in flight
        if (c <= NCH - 3)      asm volatile("s_waitcnt vmcnt(8)" ::: "memory");
        else if (c == NCH - 2) asm volatile("s_waitcnt vmcnt(4)" ::: "memory");
        else                   asm volatile("s_waitcnt vmcnt(0)" ::: "memory");
        __builtin_amdgcn_s_barrier();
        __builtin_amdgcn_sched_barrier(0);

        if (c + 3 < NCH) STAGE((c + 3) & 3, c + 3);   // ring slot free: readers done

        const int buf = c & 3;
        f16x8 a[8], b[4];
#pragma unroll
        for (int m = 0; m < 8; ++m)
            a[m] = *(const f16x8*)&lds[buf][0][g][wm * 128 + m * 16 + r][0];
#pragma unroll
        for (int n = 0; n < 4; ++n)
            b[n] = *(const f16x8*)&lds[buf][1][g][wn * 64 + n * 16 + r][0];

        __builtin_amdgcn_s_setprio(1);
#pragma unroll
        for (int m = 0; m < 8; ++m)
#pragma unroll
            for (int n = 0; n < 4; ++n)
                acc[m][n] = __builtin_amdgcn_mfma_f32_16x16x32_f16(
                    a[m], b[n], acc[m][n], 0, 0, 0);
        __builtin_amdgcn_s_setprio(0);
        __builtin_amdgcn_sched_barrier(0);
    }
#undef STAGE

    __syncthreads();   // full drain before LDS reuse

    // ---- epilogue: per-row top-2 over this block's 256 cols ----
    float kn[4];
#pragma unroll
    for (int n = 0; n < 4; ++n) kn[n] = knorm[colBase + wn * 64 + n * 16 + r];

    float* mv = (float*)&lds[0][0][0][0][0];      // [4 wn][256 row][2]
    int*   mi = (int*)(mv + 4 * 256 * 2);         // 8 KiB + 8 KiB

#pragma unroll
    for (int m = 0; m < 8; ++m) {
#pragma unroll
        for (int q = 0; q < 4; ++q) {
            float v1 = 3.0e38f, v2 = 3.0e38f;
            int   i1 = 0x7fffffff, i2 = 0x7fffffff;
#pragma unroll
            for (int n = 0; n < 4; ++n) {
                int col = colBase + wn * 64 + n * 16 + r;
                float d = fmaf(-2.0f, acc[m][n][q], kn[n]);
                if (d < v1 || (d == v1 && col < i1)) {
                    v2 = v1; i2 = i1; v1 = d; i1 = col;
                } else if (d < v2 || (d == v2 && col < i2)) {
                    v2 = d; i2 = col;
                }
            }
#pragma unroll
            for (int msk = 1; msk < 16; msk <<= 1) {
                float ov1 = __shfl_xor(v1, msk, 64);
                int   oi1 = __shfl_xor(i1, msk, 64);
                float ov2 = __shfl_xor(v2, msk, 64);
                int   oi2 = __shfl_xor(i2, msk, 64);
                bool ob = (ov1 < v1) || (ov1 == v1 && oi1 < i1);
                float nbv = ob ? ov1 : v1;  int nbi = ob ? oi1 : i1;
                float c1v = ob ? ov2 : v2;  int c1i = ob ? oi2 : i2;
                float c2v = ob ? v1 : ov1;  int c2i = ob ? i1 : oi1;
                bool cb2 = (c2v < c1v) || (c2v == c1v && c2i < c1i);
                v1 = nbv; i1 = nbi;
                v2 = cb2 ? c2v : c1v; i2 = cb2 ? c2i : c1i;
            }
            if (r == 0) {
                int lrow = wm * 128 + m * 16 + g * 4 + q;   // 0..255
                mv[(wn * 256 + lrow) * 2 + 0] = v1;
                mv[(wn * 256 + lrow) * 2 + 1] = v2;
                mi[(wn * 256 + lrow) * 2 + 0] = i1;
                mi[(wn * 256 + lrow) * 2 + 1] = i2;
            }
        }
    }
    __syncthreads();

    // merge 4 wn-waves' top-2 -> per-row top-2 over 256 cols
    if (tid < 256) {
        float V1 = 3.0e38f, V2 = 3.0e38f;
        int   I1 = 0x7fffffff, I2 = 0x7fffffff;
#pragma unroll
        for (int s = 0; s < 8; ++s) {
            float d = mv[((s >> 1) * 256 + tid) * 2 + (s & 1)];
            int   ci = mi[((s >> 1) * 256 + tid) * 2 + (s & 1)];
            if (d < V1 || (d == V1 && ci < I1)) {
                V2 = V1; I2 = I1; V1 = d; I1 = ci;
            } else if (d < V2 || (d == V2 && ci < I2)) {
                V2 = d; I2 = ci;
            }
        }
        size_t o = (size_t)cb * BNR + rowBase + tid;
        pv1[o] = V1; pi1[o] = I1;
        pv2[o] = V2; pi2[o] = I2;
    }
}

// ---------------- refine: top-8 by fp32 value, exact fp64 distances ----------------
__global__ void refine_k(const float* __restrict__ x, const float* __restrict__ emb,
                         const float* __restrict__ pv1, const int* __restrict__ pi1,
                         const float* __restrict__ pv2, const int* __restrict__ pi2,
                         float* __restrict__ out_idx) {
    int row  = blockIdx.x * 4 + (threadIdx.x >> 6);
    int lane = threadIdx.x & 63;
    float v; int idx;
    if (lane < NSETS) {
        v = pv1[(size_t)lane * BNR + row]; idx = pi1[(size_t)lane * BNR + row];
    } else {
        v = pv2[(size_t)(lane - NSETS) * BNR + row]; idx = pi2[(size_t)(lane - NSETS) * BNR + row];
    }
    int cand[8];
#pragma unroll
    for (int b = 0; b < 8; ++b) {
        float mvv = v; int mii = idx;
#pragma unroll
        for (int msk = 1; msk < 64; msk <<= 1) {
            float ov = __shfl_xor(mvv, msk, 64);
            int   oi = __shfl_xor(mii, msk, 64);
            if (ov < mvv || (ov == mvv && oi < mii)) { mvv = ov; mii = oi; }
        }
        cand[b] = mii;
        if (v == mvv && idx == mii) { v = 3.0e38f; idx = 0x7fffffff; }
    }
    int gid = lane >> 3, gl = lane & 7;
    int myc = cand[gid];
    const float* qp = x + (size_t)row * C;
    const float* kp = emb + (size_t)myc * C;
    double s = 0.0;
#pragma unroll 4
    for (int j = gl * 64; j < gl * 64 + 64; j += 4) {
        float4 q4 = *(const float4*)(qp + j);
        float4 k4 = *(const float4*)(kp + j);
        double d0 = (double)q4.x - (double)k4.x;
        double d1 = (double)q4.y - (double)k4.y;
        double d2 = (double)q4.z - (double)k4.z;
        double d3 = (double)q4.w - (double)k4.w;
        s += d0 * d0 + d1 * d1 + d2 * d2 + d3 * d3;
    }
    s += __shfl_xor(s, 1, 64);
    s += __shfl_xor(s, 2, 64);
    s += __shfl_xor(s, 4, 64);
    double dv = (gl == 0) ? s : 1.0e300;
    int    di = (gl == 0) ? myc : 0x7fffffff;
#pragma unroll
    for (int msk = 8; msk < 64; msk <<= 1) {
        double ov = __shfl_xor(dv, msk, 64);
        int    oi = __shfl_xor(di, msk, 64);
        if (ov < dv || (ov == dv && oi < di)) { dv = ov; di = oi; }
    }
    if (lane == 0) out_idx[row] = (float)di;
}

// ---------------- gather z_st + scatter onehot ones ----------------
__global__ void gather_k(const float* __restrict__ emb, const float* __restrict__ out_idx,
                         float* __restrict__ zst, float* __restrict__ onehot) {
    int row = blockIdx.x;
    int idx = (int)out_idx[row];
    const float4* src = (const float4*)(emb + (size_t)idx * C);
    float4* dst = (float4*)(zst + (size_t)row * C);
    dst[threadIdx.x] = src[threadIdx.x];
    if (threadIdx.x == 0) onehot[(size_t)row * M + idx] = 1.0f;
}

// ---------------- perplexity via LDS histogram ----------------
__global__ void perp_k(const float* __restrict__ out_idx, float* __restrict__ out_perp) {
    __shared__ int hist[M];
    __shared__ float red[256];
    int tid = threadIdx.x;
    for (int j = tid; j < M; j += 256) hist[j] = 0;
    __syncthreads();
    for (int j = tid; j < BNR; j += 256) atomicAdd(&hist[(int)out_idx[j]], 1);
    __syncthreads();
    float s = 0.f;
    for (int j = tid; j < M; j += 256) {
        float pb = (float)hist[j] * (1.0f / (float)BNR);
        s += pb * logf(pb + 1e-10f);
    }
    red[tid] = s; __syncthreads();
    for (int o = 128; o > 0; o >>= 1) {
        if (tid < o) red[tid] += red[tid + o];
        __syncthreads();
    }
    if (tid == 0) out_perp[0] = expf(-red[0]);
}

extern "C" void kernel_launch(void* const* d_in, const int* in_sizes, int n_in,
                              void* d_out, int out_size, void* d_ws, size_t ws_size,
                              hipStream_t stream) {
    const float* x   = (const float*)d_in[0];
    const float* emb = (const float*)d_in[1];

    float* out        = (float*)d_out;
    float* out_zst    = out;                              // 8388608
    float* out_idx    = out + (size_t)BNR * C;            // 16384
    float* out_onehot = out_idx + BNR;                    // 134217728
    float* out_perp   = out_onehot + (size_t)BNR * M;     // 1

    // scratch lives in the onehot region (memset afterwards): ~34 MiB used
    u16*   x2    = (u16*)out_onehot;                      // 16 MiB
    u16*   e2    = x2 + (size_t)BNR * C;                  // 8 MiB
    float* knorm = (float*)(e2 + (size_t)M * C);
    float* pv1   = knorm + M;
    float* pv2   = pv1 + (size_t)NSETS * BNR;
    int*   pi1   = (int*)(pv2 + (size_t)NSETS * BNR);
    int*   pi2   = pi1 + (size_t)NSETS * BNR;

    cvt_h_k<<<(BNR * C / 8) / 256, 256, 0, stream>>>(x, x2);
    cvt_h_k<<<(M * C / 8) / 256, 256, 0, stream>>>(emb, e2);
    knorm_k<<<64, 256, 0, stream>>>(emb, knorm);
    mfma_argmin_k<<<(BNR / BM) * (M / BN), 512, 0, stream>>>(
        x2, e2, knorm, pv1, pi1, pv2, pi2);
    refine_k<<<BNR / 4, 256, 0, stream>>>(x, emb, pv1, pi1, pv2, pi2, out_idx);

    hipMemsetAsync(out_onehot, 0, (size_t)BNR * M * sizeof(float), stream);
    gather_k<<<BNR, 128, 0, stream>>>(emb, out_idx, out_zst, out_onehot);
    perp_k<<<1, 256, 0, stream>>>(out_idx, out_perp);
}

// Round 9
// 661.278 us; speedup vs baseline: 1.8684x; 1.0006x over previous
//
#include <hip/hip_runtime.h>
#include <cstdint>
#include <cstddef>

#define BNR 16384   // b*n rows
#define C   512     // feature dim
#define M   8192    // codebook size
#define BM  256
#define BN  256
#define BK  32
#define NCH 16      // K chunks = C/BK
#define NSETS 32    // column blocks (8192/256)

typedef float f32x4 __attribute__((ext_vector_type(4)));
typedef _Float16 f16x8 __attribute__((ext_vector_type(8)));
typedef unsigned short u16;

static __device__ __forceinline__ u16 h_bits(_Float16 h) {
    union { _Float16 h; u16 u; } x; x.h = h; return x.u;
}
static __device__ __forceinline__ void gl_lds16(const void* g, void* l) {
    __builtin_amdgcn_global_load_lds(
        (const __attribute__((address_space(1))) void*)g,
        (__attribute__((address_space(3))) void*)l, 16, 0, 0);
}

// ---------------- ||k||^2 per codebook row (exact fp32) ----------------
__global__ void knorm_k(const float* __restrict__ emb, float* __restrict__ knorm) {
    int gw   = (blockIdx.x * blockDim.x + threadIdx.x) >> 6;
    int lane = threadIdx.x & 63;
    int nw   = (gridDim.x * blockDim.x) >> 6;
    for (int row = gw; row < M; row += nw) {
        const float4* p = (const float4*)(emb + (size_t)row * C);
        float s = 0.f;
#pragma unroll
        for (int j = 0; j < 2; ++j) {
            float4 v = p[lane + 64 * j];
            s += v.x * v.x + v.y * v.y + v.z * v.z + v.w * v.w;
        }
#pragma unroll
        for (int o = 32; o > 0; o >>= 1) s += __shfl_down(s, o, 64);
        if (lane == 0) knorm[row] = s;
    }
}

// ---------------- fp32 -> fp16 (hi only), 8 elems/thread ----------------
__global__ void cvt_h_k(const float* __restrict__ in, u16* __restrict__ outp) {
    int t = blockIdx.x * 256 + threadIdx.x;
    const float4* p = (const float4*)in;
    float4 a = p[2 * t], b = p[2 * t + 1];
    u16 o[8] = { h_bits((_Float16)a.x), h_bits((_Float16)a.y),
                 h_bits((_Float16)a.z), h_bits((_Float16)a.w),
                 h_bits((_Float16)b.x), h_bits((_Float16)b.y),
                 h_bits((_Float16)b.z), h_bits((_Float16)b.w) };
    *(ushort4*)(outp + 8 * t)     = *(ushort4*)(o);
    *(ushort4*)(outp + 8 * t + 4) = *(ushort4*)(o + 4);
}

// ---------------- MFMA distance GEMM + per-colblock top-2 ----------------
// 2048 blocks x 512 threads (8 waves, 2M x 4N, per-wave 128x64 = acc[8][4]).
// 4-deep LDS ring (BK=32, 32 KiB/tile), stage tile c+3 each chunk,
// ONE raw s_barrier per chunk, counted s_waitcnt vmcnt(8) (drain-0 only in tail).
// LDS tile layout [kb(4)][row(256)][8] u16: conflict-free ds_read_b128.
__global__ __launch_bounds__(512, 2) void mfma_argmin_k(
    const u16* __restrict__ x2, const u16* __restrict__ e2,
    const float* __restrict__ knorm,
    float* __restrict__ pv1, int* __restrict__ pi1,
    float* __restrict__ pv2, int* __restrict__ pi2) {
    __shared__ __align__(16) u16 lds[4][2][4][256][8];   // 128 KiB

    const int tid  = threadIdx.x;
    const int lane = tid & 63;
    const int w    = tid >> 6;          // 0..7
    const int wm   = w >> 2, wn = w & 3;
    const int g    = lane >> 4, r = lane & 15;

    // supertile XCD swizzle: XCD gets 4 supertiles of 8rb x 8cb;
    // concurrent window (32 blocks) = 8 A-panels + 4 B-panels = 3 MiB <= L2.
    {
    }
    const int xk = blockIdx.x & 7, j = blockIdx.x >> 3;
    const int st = xk + 8 * (j >> 6);       // supertile 0..31
    const int p  = j & 63;
    const int rb = (st & 7) * 8 + (p & 7);  // 0..63
    const int cb = (st >> 3) * 8 + (p >> 3);// 0..31
    const int rowBase = rb * BM, colBase = cb * BN;

    f32x4 acc[8][4];
#pragma unroll
    for (int m = 0; m < 8; ++m)
#pragma unroll
        for (int n = 0; n < 4; ++n) acc[m][n] = (f32x4)(0.0f);

    const u16* abase = x2 + (size_t)rowBase * C;
    const u16* bbase = e2 + (size_t)colBase * C;

#define STAGE(buf, c)                                                          \
    {                                                                          \
        _Pragma("unroll")                                                      \
        for (int it = 0; it < 2; ++it) {                                       \
            int u = it * 512 + tid;                                            \
            int urow = u & 255, ukb = u >> 8;                                  \
            gl_lds16(abase + (size_t)urow * C + (c) * BK + ukb * 8,            \
                     &lds[buf][0][ukb][urow][0]);                              \
            gl_lds16(bbase + (size_t)urow * C + (c) * BK + ukb * 8,            \
                     &lds[buf][1][ukb][urow][0]);                              \
        }                                                                      \
    }

    // prologue: 3 tiles in flight (12 loads/thread)
    STAGE(0, 0);
    STAGE(1, 1);
    STAGE(2, 2);

#pragma unroll 1
    for (int c = 0; c < NCH; ++c) {
        // counted drain: T_c complete; keep up to 2 newer tiles in flight
        if (c <= NCH - 3)      asm volatile("s_waitcnt vmcnt(8)" ::: "memory");
        else if (c == NCH - 2) asm volatile("s_waitcnt vmcnt(4)" ::: "memory");
        else                   asm volatile("s_waitcnt vmcnt(0)" ::: "memory");
        __builtin_amdgcn_s_barrier();
        __builtin_amdgcn_sched_barrier(0);

        if (c + 3 < NCH) STAGE((c + 3) & 3, c + 3);   // ring slot free: readers done

        const int buf = c & 3;
        f16x8 a[8], b[4];
#pragma unroll
        for (int m = 0; m < 8; ++m)
            a[m] = *(const f16x8*)&lds[buf][0][g][wm * 128 + m * 16 + r][0];
#pragma unroll
        for (int n = 0; n < 4; ++n)
            b[n] = *(const f16x8*)&lds[buf][1][g][wn * 64 + n * 16 + r][0];

        __builtin_amdgcn_s_setprio(1);
#pragma unroll
        for (int m = 0; m < 8; ++m)
#pragma unroll
            for (int n = 0; n < 4; ++n)
                acc[m][n] = __builtin_amdgcn_mfma_f32_16x16x32_f16(
                    a[m], b[n], acc[m][n], 0, 0, 0);
        __builtin_amdgcn_s_setprio(0);
        __builtin_amdgcn_sched_barrier(0);
    }
#undef STAGE

    __syncthreads();   // full drain before LDS reuse

    // ---- epilogue: per-row top-2 over this block's 256 cols ----
    float kn[4];
#pragma unroll
    for (int n = 0; n < 4; ++n) kn[n] = knorm[colBase + wn * 64 + n * 16 + r];

    float* mv = (float*)&lds[0][0][0][0][0];      // [4 wn][256 row][2]
    int*   mi = (int*)(mv + 4 * 256 * 2);         // 8 KiB + 8 KiB

#pragma unroll
    for (int m = 0; m < 8; ++m) {
#pragma unroll
        for (int q = 0; q < 4; ++q) {
            float v1 = 3.0e38f, v2 = 3.0e38f;
            int   i1 = 0x7fffffff, i2 = 0x7fffffff;
#pragma unroll
            for (int n = 0; n < 4; ++n) {
                int col = colBase + wn * 64 + n * 16 + r;
                float d = fmaf(-2.0f, acc[m][n][q], kn[n]);
                if (d < v1 || (d == v1 && col < i1)) {
                    v2 = v1; i2 = i1; v1 = d; i1 = col;
                } else if (d < v2 || (d == v2 && col < i2)) {
                    v2 = d; i2 = col;
                }
            }
#pragma unroll
            for (int msk = 1; msk < 16; msk <<= 1) {
                float ov1 = __shfl_xor(v1, msk, 64);
                int   oi1 = __shfl_xor(i1, msk, 64);
                float ov2 = __shfl_xor(v2, msk, 64);
                int   oi2 = __shfl_xor(i2, msk, 64);
                bool ob = (ov1 < v1) || (ov1 == v1 && oi1 < i1);
                float nbv = ob ? ov1 : v1;  int nbi = ob ? oi1 : i1;
                float c1v = ob ? ov2 : v2;  int c1i = ob ? oi2 : i2;
                float c2v = ob ? v1 : ov1;  int c2i = ob ? i1 : oi1;
                bool cb2 = (c2v < c1v) || (c2v == c1v && c2i < c1i);
                v1 = nbv; i1 = nbi;
                v2 = cb2 ? c2v : c1v; i2 = cb2 ? c2i : c1i;
            }
            if (r == 0) {
                int lrow = wm * 128 + m * 16 + g * 4 + q;   // 0..255
                mv[(wn * 256 + lrow) * 2 + 0] = v1;
                mv[(wn * 256 + lrow) * 2 + 1] = v2;
                mi[(wn * 256 + lrow) * 2 + 0] = i1;
                mi[(wn * 256 + lrow) * 2 + 1] = i2;
            }
        }
    }
    __syncthreads();

    // merge 4 wn-waves' top-2 -> per-row top-2 over 256 cols
    if (tid < 256) {
        float V1 = 3.0e38f, V2 = 3.0e38f;
        int   I1 = 0x7fffffff, I2 = 0x7fffffff;
#pragma unroll
        for (int s = 0; s < 8; ++s) {
            float d = mv[((s >> 1) * 256 + tid) * 2 + (s & 1)];
            int   ci = mi[((s >> 1) * 256 + tid) * 2 + (s & 1)];
            if (d < V1 || (d == V1 && ci < I1)) {
                V2 = V1; I2 = I1; V1 = d; I1 = ci;
            } else if (d < V2 || (d == V2 && ci < I2)) {
                V2 = d; I2 = ci;
            }
        }
        size_t o = (size_t)cb * BNR + rowBase + tid;
        pv1[o] = V1; pi1[o] = I1;
        pv2[o] = V2; pi2[o] = I2;
    }
}

// ---------------- refine: top-8 by fp32 value, exact fp64 distances ----------------
__global__ void refine_k(const float* __restrict__ x, const float* __restrict__ emb,
                         const float* __restrict__ pv1, const int* __restrict__ pi1,
                         const float* __restrict__ pv2, const int* __restrict__ pi2,
                         float* __restrict__ out_idx) {
    int row  = blockIdx.x * 4 + (threadIdx.x >> 6);
    int lane = threadIdx.x & 63;
    float v; int idx;
    if (lane < NSETS) {
        v = pv1[(size_t)lane * BNR + row]; idx = pi1[(size_t)lane * BNR + row];
    } else {
        v = pv2[(size_t)(lane - NSETS) * BNR + row]; idx = pi2[(size_t)(lane - NSETS) * BNR + row];
    }
    int cand[8];
#pragma unroll
    for (int b = 0; b < 8; ++b) {
        float mvv = v; int mii = idx;
#pragma unroll
        for (int msk = 1; msk < 64; msk <<= 1) {
            float ov = __shfl_xor(mvv, msk, 64);
            int   oi = __shfl_xor(mii, msk, 64);
            if (ov < mvv || (ov == mvv && oi < mii)) { mvv = ov; mii = oi; }
        }
        cand[b] = mii;
        if (v == mvv && idx == mii) { v = 3.0e38f; idx = 0x7fffffff; }
    }
    int gid = lane >> 3, gl = lane & 7;
    int myc = cand[gid];
    const float* qp = x + (size_t)row * C;
    const float* kp = emb + (size_t)myc * C;
    double s = 0.0;
#pragma unroll 4
    for (int j = gl * 64; j < gl * 64 + 64; j += 4) {
        float4 q4 = *(const float4*)(qp + j);
        float4 k4 = *(const float4*)(kp + j);
        double d0 = (double)q4.x - (double)k4.x;
        double d1 = (double)q4.y - (double)k4.y;
        double d2 = (double)q4.z - (double)k4.z;
        double d3 = (double)q4.w - (double)k4.w;
        s += d0 * d0 + d1 * d1 + d2 * d2 + d3 * d3;
    }
    s += __shfl_xor(s, 1, 64);
    s += __shfl_xor(s, 2, 64);
    s += __shfl_xor(s, 4, 64);
    double dv = (gl == 0) ? s : 1.0e300;
    int    di = (gl == 0) ? myc : 0x7fffffff;
#pragma unroll
    for (int msk = 8; msk < 64; msk <<= 1) {
        double ov = __shfl_xor(dv, msk, 64);
        int    oi = __shfl_xor(di, msk, 64);
        if (ov < dv || (ov == dv && oi < di)) { dv = ov; di = oi; }
    }
    if (lane == 0) out_idx[row] = (float)di;
}

// ---------------- gather z_st + scatter onehot ones ----------------
__global__ void gather_k(const float* __restrict__ emb, const float* __restrict__ out_idx,
                         float* __restrict__ zst, float* __restrict__ onehot) {
    int row = blockIdx.x;
    int idx = (int)out_idx[row];
    const float4* src = (const float4*)(emb + (size_t)idx * C);
    float4* dst = (float4*)(zst + (size_t)row * C);
    dst[threadIdx.x] = src[threadIdx.x];
    if (threadIdx.x == 0) onehot[(size_t)row * M + idx] = 1.0f;
}

// ---------------- perplexity via LDS histogram ----------------
__global__ void perp_k(const float* __restrict__ out_idx, float* __restrict__ out_perp) {
    __shared__ int hist[M];
    __shared__ float red[256];
    int tid = threadIdx.x;
    for (int j = tid; j < M; j += 256) hist[j] = 0;
    __syncthreads();
    for (int j = tid; j < BNR; j += 256) atomicAdd(&hist[(int)out_idx[j]], 1);
    __syncthreads();
    float s = 0.f;
    for (int j = tid; j < M; j += 256) {
        float pb = (float)hist[j] * (1.0f / (float)BNR);
        s += pb * logf(pb + 1e-10f);
    }
    red[tid] = s; __syncthreads();
    for (int o = 128; o > 0; o >>= 1) {
        if (tid < o) red[tid] += red[tid + o];
        __syncthreads();
    }
    if (tid == 0) out_perp[0] = expf(-red[0]);
}

extern "C" void kernel_launch(void* const* d_in, const int* in_sizes, int n_in,
                              void* d_out, int out_size, void* d_ws, size_t ws_size,
                              hipStream_t stream) {
    const float* x   = (const float*)d_in[0];
    const float* emb = (const float*)d_in[1];

    float* out        = (float*)d_out;
    float* out_zst    = out;                              // 8388608
    float* out_idx    = out + (size_t)BNR * C;            // 16384
    float* out_onehot = out_idx + BNR;                    // 134217728
    float* out_perp   = out_onehot + (size_t)BNR * M;     // 1

    // scratch lives in the onehot region (memset afterwards): ~34 MiB used
    u16*   x2    = (u16*)out_onehot;                      // 16 MiB
    u16*   e2    = x2 + (size_t)BNR * C;                  // 8 MiB
    float* knorm = (float*)(e2 + (size_t)M * C);
    float* pv1   = knorm + M;
    float* pv2   = pv1 + (size_t)NSETS * BNR;
    int*   pi1   = (int*)(pv2 + (size_t)NSETS * BNR);
    int*   pi2   = pi1 + (size_t)NSETS * BNR;

    cvt_h_k<<<(BNR * C / 8) / 256, 256, 0, stream>>>(x, x2);
    cvt_h_k<<<(M * C / 8) / 256, 256, 0, stream>>>(emb, e2);
    knorm_k<<<64, 256, 0, stream>>>(emb, knorm);
    mfma_argmin_k<<<(BNR / BM) * (M / BN), 512, 0, stream>>>(
        x2, e2, knorm, pv1, pi1, pv2, pi2);
    refine_k<<<BNR / 4, 256, 0, stream>>>(x, emb, pv1, pi1, pv2, pi2, out_idx);

    hipMemsetAsync(out_onehot, 0, (size_t)BNR * M * sizeof(float), stream);
    gather_k<<<BNR, 128, 0, stream>>>(emb, out_idx, out_zst, out_onehot);
    perp_k<<<1, 256, 0, stream>>>(out_idx, out_perp);
}

// Round 10
// 588.307 us; speedup vs baseline: 2.1002x; 1.1240x over previous
//
#include <hip/hip_runtime.h>
#include <cstdint>
#include <cstddef>

#define BNR 16384   // b*n rows
#define C   512     // feature dim
#define M   8192    // codebook size
#define BM  256
#define BN  256
#define BK  32
#define NCH 16      // K chunks = C/BK
#define NSETS 32    // column blocks (8192/256)

// tiled operand layout: [block256][chunk16][kb4][row256][8 u16]
// per (block,chunk) tile = 1024 units of 16B = 16 KiB; per block = 128 KiB.
#define TILE_U16   8192      // u16 per (block,chunk) tile
#define BLOCK_U16  131072    // u16 per block (16 chunks)

typedef float f32x4 __attribute__((ext_vector_type(4)));
typedef _Float16 f16x8 __attribute__((ext_vector_type(8)));
typedef unsigned short u16;

static __device__ __forceinline__ u16 h_bits(_Float16 h) {
    union { _Float16 h; u16 u; } x; x.h = h; return x.u;
}
static __device__ __forceinline__ void gl_lds16(const void* g, void* l) {
    __builtin_amdgcn_global_load_lds(
        (const __attribute__((address_space(1))) void*)g,
        (__attribute__((address_space(3))) void*)l, 16, 0, 0);
}

// ---------------- ||k||^2 per codebook row (exact fp32) ----------------
__global__ void knorm_k(const float* __restrict__ emb, float* __restrict__ knorm) {
    int gw   = (blockIdx.x * blockDim.x + threadIdx.x) >> 6;
    int lane = threadIdx.x & 63;
    int nw   = (gridDim.x * blockDim.x) >> 6;
    for (int row = gw; row < M; row += nw) {
        const float4* p = (const float4*)(emb + (size_t)row * C);
        float s = 0.f;
#pragma unroll
        for (int j = 0; j < 2; ++j) {
            float4 v = p[lane + 64 * j];
            s += v.x * v.x + v.y * v.y + v.z * v.z + v.w * v.w;
        }
#pragma unroll
        for (int o = 32; o > 0; o >>= 1) s += __shfl_down(s, o, 64);
        if (lane == 0) knorm[row] = s;
    }
}

// ---------------- fp32 -> fp16 hi, written in TILED layout ----------------
// One thread per 16B output unit, OUTPUT-linear (coalesced HBM writes;
// the 16B-scattered reads are absorbed by L2).
// unit o: q = o & 1023 -> kb = q>>8, row = q&255 ; c = (o>>10)&15 ; blk = o>>14
__global__ void cvt_tile_k(const float* __restrict__ in, u16* __restrict__ outp) {
    int o = blockIdx.x * 256 + threadIdx.x;
    int q = o & 1023, kb = q >> 8, row = q & 255;
    int c = (o >> 10) & 15, blk = o >> 14;
    int grow = blk * 256 + row;
    int k0 = c * BK + kb * 8;
    const float4* src = (const float4*)(in + (size_t)grow * C + k0);
    float4 a = src[0], b = src[1];
    u16 v[8] = { h_bits((_Float16)a.x), h_bits((_Float16)a.y),
                 h_bits((_Float16)a.z), h_bits((_Float16)a.w),
                 h_bits((_Float16)b.x), h_bits((_Float16)b.y),
                 h_bits((_Float16)b.z), h_bits((_Float16)b.w) };
    u16* dst = outp + (size_t)o * 8;
    *(ushort4*)(dst)     = *(ushort4*)(v);
    *(ushort4*)(dst + 4) = *(ushort4*)(v + 4);
}

// ---------------- MFMA distance GEMM + per-colblock top-2 ----------------
// 2048 blocks x 512 threads (8 waves, 2M x 4N, per-wave 128x64 = acc[8][4]).
// 4-deep LDS ring (BK=32, 32 KiB/tile-pair), stage tile c+3 each chunk,
// ONE s_barrier per chunk, counted vmcnt(8) (drain-0 only in tail).
// Operands pre-tiled in global: STAGE is base + u*16B -> fully coalesced,
// LDS lands in [kb][row][8] (conflict-free ds_read_b128) for free.
__global__ __launch_bounds__(512, 2) void mfma_argmin_k(
    const u16* __restrict__ x2t, const u16* __restrict__ e2t,
    const float* __restrict__ knorm,
    float* __restrict__ pv1, int* __restrict__ pi1,
    float* __restrict__ pv2, int* __restrict__ pi2) {
    __shared__ __align__(16) u16 ldsA[4][4][256][8];   // 64 KiB
    __shared__ __align__(16) u16 ldsB[4][4][256][8];   // 64 KiB

    const int tid  = threadIdx.x;
    const int lane = tid & 63;
    const int w    = tid >> 6;          // 0..7
    const int wm   = w >> 2, wn = w & 3;
    const int g    = lane >> 4, r = lane & 15;

    // supertile XCD swizzle: XCD gets 4 supertiles of 8rb x 8cb;
    // concurrent window (32 blocks/XCD) = 8 A-panels + 4 B-panels <= L2.
    const int xk = blockIdx.x & 7, j = blockIdx.x >> 3;
    const int st = xk + 8 * (j >> 6);        // supertile 0..31
    const int p  = j & 63;
    const int rb = (st & 7) * 8 + (p & 7);   // 0..63
    const int cb = (st >> 3) * 8 + (p >> 3); // 0..31
    const int rowBase = rb * BM, colBase = cb * BN;

    f32x4 acc[8][4];
#pragma unroll
    for (int m = 0; m < 8; ++m)
#pragma unroll
        for (int n = 0; n < 4; ++n) acc[m][n] = (f32x4)(0.0f);

    const u16* aT = x2t + (size_t)rb * BLOCK_U16;
    const u16* bT = e2t + (size_t)cb * BLOCK_U16;

#define STAGE(buf, c)                                                          \
    {                                                                          \
        _Pragma("unroll")                                                      \
        for (int it = 0; it < 2; ++it) {                                       \
            int u = it * 512 + tid;                                            \
            gl_lds16(aT + (size_t)(c) * TILE_U16 + u * 8,                      \
                     &ldsA[buf][0][0][0] + u * 8);                             \
            gl_lds16(bT + (size_t)(c) * TILE_U16 + u * 8,                      \
                     &ldsB[buf][0][0][0] + u * 8);                             \
        }                                                                      \
    }

    // prologue: 3 tiles in flight (12 loads/thread)
    STAGE(0, 0);
    STAGE(1, 1);
    STAGE(2, 2);

#pragma unroll 1
    for (int c = 0; c < NCH; ++c) {
        // counted drain: tile c complete; keep up to 2 newer tiles in flight
        if (c <= NCH - 3)      asm volatile("s_waitcnt vmcnt(8)" ::: "memory");
        else if (c == NCH - 2) asm volatile("s_waitcnt vmcnt(4)" ::: "memory");
        else                   asm volatile("s_waitcnt vmcnt(0)" ::: "memory");
        __builtin_amdgcn_s_barrier();
        __builtin_amdgcn_sched_barrier(0);

        if (c + 3 < NCH) STAGE((c + 3) & 3, c + 3);   // ring slot free: readers done

        const int buf = c & 3;
        f16x8 a[8], b[4];
#pragma unroll
        for (int m = 0; m < 8; ++m)
            a[m] = *(const f16x8*)&ldsA[buf][g][wm * 128 + m * 16 + r][0];
#pragma unroll
        for (int n = 0; n < 4; ++n)
            b[n] = *(const f16x8*)&ldsB[buf][g][wn * 64 + n * 16 + r][0];

        __builtin_amdgcn_s_setprio(1);
#pragma unroll
        for (int m = 0; m < 8; ++m)
#pragma unroll
            for (int n = 0; n < 4; ++n)
                acc[m][n] = __builtin_amdgcn_mfma_f32_16x16x32_f16(
                    a[m], b[n], acc[m][n], 0, 0, 0);
        __builtin_amdgcn_s_setprio(0);
        __builtin_amdgcn_sched_barrier(0);
    }
#undef STAGE

    __syncthreads();   // all loads retired (vmcnt(0) at c=15) before LDS reuse

    // ---- epilogue: per-row top-2 over this block's 256 cols ----
    float kn[4];
#pragma unroll
    for (int n = 0; n < 4; ++n) kn[n] = knorm[colBase + wn * 64 + n * 16 + r];

    float* mv = (float*)&ldsA[0][0][0][0];        // [4 wn][256 row][2]
    int*   mi = (int*)(mv + 4 * 256 * 2);         // 8 KiB + 8 KiB

#pragma unroll
    for (int m = 0; m < 8; ++m) {
#pragma unroll
        for (int q = 0; q < 4; ++q) {
            float v1 = 3.0e38f, v2 = 3.0e38f;
            int   i1 = 0x7fffffff, i2 = 0x7fffffff;
#pragma unroll
            for (int n = 0; n < 4; ++n) {
                int col = colBase + wn * 64 + n * 16 + r;
                float d = fmaf(-2.0f, acc[m][n][q], kn[n]);
                if (d < v1 || (d == v1 && col < i1)) {
                    v2 = v1; i2 = i1; v1 = d; i1 = col;
                } else if (d < v2 || (d == v2 && col < i2)) {
                    v2 = d; i2 = col;
                }
            }
#pragma unroll
            for (int msk = 1; msk < 16; msk <<= 1) {
                float ov1 = __shfl_xor(v1, msk, 64);
                int   oi1 = __shfl_xor(i1, msk, 64);
                float ov2 = __shfl_xor(v2, msk, 64);
                int   oi2 = __shfl_xor(i2, msk, 64);
                bool ob = (ov1 < v1) || (ov1 == v1 && oi1 < i1);
                float nbv = ob ? ov1 : v1;  int nbi = ob ? oi1 : i1;
                float c1v = ob ? ov2 : v2;  int c1i = ob ? oi2 : i2;
                float c2v = ob ? v1 : ov1;  int c2i = ob ? i1 : oi1;
                bool cb2 = (c2v < c1v) || (c2v == c1v && c2i < c1i);
                v1 = nbv; i1 = nbi;
                v2 = cb2 ? c2v : c1v; i2 = cb2 ? c2i : c1i;
            }
            if (r == 0) {
                int lrow = wm * 128 + m * 16 + g * 4 + q;   // 0..255
                mv[(wn * 256 + lrow) * 2 + 0] = v1;
                mv[(wn * 256 + lrow) * 2 + 1] = v2;
                mi[(wn * 256 + lrow) * 2 + 0] = i1;
                mi[(wn * 256 + lrow) * 2 + 1] = i2;
            }
        }
    }
    __syncthreads();

    // merge 4 wn-waves' top-2 -> per-row top-2 over 256 cols
    if (tid < 256) {
        float V1 = 3.0e38f, V2 = 3.0e38f;
        int   I1 = 0x7fffffff, I2 = 0x7fffffff;
#pragma unroll
        for (int s = 0; s < 8; ++s) {
            float d = mv[((s >> 1) * 256 + tid) * 2 + (s & 1)];
            int   ci = mi[((s >> 1) * 256 + tid) * 2 + (s & 1)];
            if (d < V1 || (d == V1 && ci < I1)) {
                V2 = V1; I2 = I1; V1 = d; I1 = ci;
            } else if (d < V2 || (d == V2 && ci < I2)) {
                V2 = d; I2 = ci;
            }
        }
        size_t o = (size_t)cb * BNR + rowBase + tid;
        pv1[o] = V1; pi1[o] = I1;
        pv2[o] = V2; pi2[o] = I2;
    }
}

// ---------------- refine: top-8 by fp32 value, exact fp64 distances ----------------
__global__ void refine_k(const float* __restrict__ x, const float* __restrict__ emb,
                         const float* __restrict__ pv1, const int* __restrict__ pi1,
                         const float* __restrict__ pv2, const int* __restrict__ pi2,
                         float* __restrict__ out_idx) {
    int row  = blockIdx.x * 4 + (threadIdx.x >> 6);
    int lane = threadIdx.x & 63;
    float v; int idx;
    if (lane < NSETS) {
        v = pv1[(size_t)lane * BNR + row]; idx = pi1[(size_t)lane * BNR + row];
    } else {
        v = pv2[(size_t)(lane - NSETS) * BNR + row]; idx = pi2[(size_t)(lane - NSETS) * BNR + row];
    }
    int cand[8];
#pragma unroll
    for (int b = 0; b < 8; ++b) {
        float mvv = v; int mii = idx;
#pragma unroll
        for (int msk = 1; msk < 64; msk <<= 1) {
            float ov = __shfl_xor(mvv, msk, 64);
            int   oi = __shfl_xor(mii, msk, 64);
            if (ov < mvv || (ov == mvv && oi < mii)) { mvv = ov; mii = oi; }
        }
        cand[b] = mii;
        if (v == mvv && idx == mii) { v = 3.0e38f; idx = 0x7fffffff; }
    }
    int gid = lane >> 3, gl = lane & 7;
    int myc = cand[gid];
    const float* qp = x + (size_t)row * C;
    const float* kp = emb + (size_t)myc * C;
    double s = 0.0;
#pragma unroll 4
    for (int j = gl * 64; j < gl * 64 + 64; j += 4) {
        float4 q4 = *(const float4*)(qp + j);
        float4 k4 = *(const float4*)(kp + j);
        double d0 = (double)q4.x - (double)k4.x;
        double d1 = (double)q4.y - (double)k4.y;
        double d2 = (double)q4.z - (double)k4.z;
        double d3 = (double)q4.w - (double)k4.w;
        s += d0 * d0 + d1 * d1 + d2 * d2 + d3 * d3;
    }
    s += __shfl_xor(s, 1, 64);
    s += __shfl_xor(s, 2, 64);
    s += __shfl_xor(s, 4, 64);
    double dv = (gl == 0) ? s : 1.0e300;
    int    di = (gl == 0) ? myc : 0x7fffffff;
#pragma unroll
    for (int msk = 8; msk < 64; msk <<= 1) {
        double ov = __shfl_xor(dv, msk, 64);
        int    oi = __shfl_xor(di, msk, 64);
        if (ov < dv || (ov == dv && oi < di)) { dv = ov; di = oi; }
    }
    if (lane == 0) out_idx[row] = (float)di;
}

// ---------------- gather z_st + scatter onehot ones ----------------
__global__ void gather_k(const float* __restrict__ emb, const float* __restrict__ out_idx,
                         float* __restrict__ zst, float* __restrict__ onehot) {
    int row = blockIdx.x;
    int idx = (int)out_idx[row];
    const float4* src = (const float4*)(emb + (size_t)idx * C);
    float4* dst = (float4*)(zst + (size_t)row * C);
    dst[threadIdx.x] = src[threadIdx.x];
    if (threadIdx.x == 0) onehot[(size_t)row * M + idx] = 1.0f;
}

// ---------------- perplexity via LDS histogram ----------------
__global__ void perp_k(const float* __restrict__ out_idx, float* __restrict__ out_perp) {
    __shared__ int hist[M];
    __shared__ float red[256];
    int tid = threadIdx.x;
    for (int j = tid; j < M; j += 256) hist[j] = 0;
    __syncthreads();
    for (int j = tid; j < BNR; j += 256) atomicAdd(&hist[(int)out_idx[j]], 1);
    __syncthreads();
    float s = 0.f;
    for (int j = tid; j < M; j += 256) {
        float pb = (float)hist[j] * (1.0f / (float)BNR);
        s += pb * logf(pb + 1e-10f);
    }
    red[tid] = s; __syncthreads();
    for (int o = 128; o > 0; o >>= 1) {
        if (tid < o) red[tid] += red[tid + o];
        __syncthreads();
    }
    if (tid == 0) out_perp[0] = expf(-red[0]);
}

extern "C" void kernel_launch(void* const* d_in, const int* in_sizes, int n_in,
                              void* d_out, int out_size, void* d_ws, size_t ws_size,
                              hipStream_t stream) {
    const float* x   = (const float*)d_in[0];
    const float* emb = (const float*)d_in[1];

    float* out        = (float*)d_out;
    float* out_zst    = out;                              // 8388608
    float* out_idx    = out + (size_t)BNR * C;            // 16384
    float* out_onehot = out_idx + BNR;                    // 134217728
    float* out_perp   = out_onehot + (size_t)BNR * M;     // 1

    // scratch lives in the onehot region (memset afterwards): ~33 MiB used
    u16*   x2t   = (u16*)out_onehot;                      // 16 MiB (tiled)
    u16*   e2t   = x2t + (size_t)BNR * C;                 // 8 MiB  (tiled)
    float* knorm = (float*)(e2t + (size_t)M * C);
    float* pv1   = knorm + M;
    float* pv2   = pv1 + (size_t)NSETS * BNR;
    int*   pi1   = (int*)(pv2 + (size_t)NSETS * BNR);
    int*   pi2   = pi1 + (size_t)NSETS * BNR;

    cvt_tile_k<<<(BNR * C / 8) / 256, 256, 0, stream>>>(x, x2t);
    cvt_tile_k<<<(M * C / 8) / 256, 256, 0, stream>>>(emb, e2t);
    knorm_k<<<64, 256, 0, stream>>>(emb, knorm);
    mfma_argmin_k<<<(BNR / BM) * (M / BN), 512, 0, stream>>>(
        x2t, e2t, knorm, pv1, pi1, pv2, pi2);
    refine_k<<<BNR / 4, 256, 0, stream>>>(x, emb, pv1, pi1, pv2, pi2, out_idx);

    hipMemsetAsync(out_onehot, 0, (size_t)BNR * M * sizeof(float), stream);
    gather_k<<<BNR, 128, 0, stream>>>(emb, out_idx, out_zst, out_onehot);
    perp_k<<<1, 256, 0, stream>>>(out_idx, out_perp);
}